// Round 2
// baseline (554.067 us; speedup 1.0000x reference)
//
#include <hip/hip_runtime.h>

#define IN_C 128
#define H1   256
#define H2   32

// ---------------- init ----------------
__global__ __launch_bounds__(256) void k_init(int* deg, int* cursor, int* gtotal, int n) {
  int i = blockIdx.x * blockDim.x + threadIdx.x;
  if (i < n) { deg[i] = 1; cursor[i] = 0; }   // deg starts at 1: self-loop
  if (i == 0) *gtotal = 0;
}

// ---------------- degree count ----------------
__global__ __launch_bounds__(256) void k_deg(const int* __restrict__ dst, int* deg, int e) {
  int i = blockIdx.x * blockDim.x + threadIdx.x;
  if (i < e) atomicAdd(&deg[dst[i]], 1);
}

// ---------------- dinv + segment offsets (wave scan + 1 atomic/wave) ----------------
__global__ __launch_bounds__(256) void k_node_prep(const int* __restrict__ deg, float* __restrict__ dinv,
                                                   int* __restrict__ offsets, int* gtotal, int n) {
  int i = blockIdx.x * blockDim.x + threadIdx.x;
  int cnt = 0;
  if (i < n) {
    int d = deg[i];
    dinv[i] = rsqrtf((float)d);
    cnt = d - 1;                  // CSR holds only real edges; self-loop handled analytically
  }
  int lane = threadIdx.x & 63;
  int val = cnt;
  #pragma unroll
  for (int off = 1; off < 64; off <<= 1) {
    int t = __shfl_up(val, off, 64);
    if (lane >= off) val += t;
  }
  int wave_total = __shfl(val, 63, 64);
  int excl = val - cnt;
  int base = 0;
  if (lane == 63) base = atomicAdd(gtotal, wave_total);
  base = __shfl(base, 63, 64);
  if (i < n) offsets[i] = base + excl;
}

// ---------------- CSR fill (counting sort by dst; src only — coef recomputed on the fly) ----------------
__global__ __launch_bounds__(256) void k_fill(const int* __restrict__ src, const int* __restrict__ dst,
                                              const int* __restrict__ offsets,
                                              int* cursor, int* __restrict__ csr_src, int e) {
  int i = blockIdx.x * blockDim.x + threadIdx.x;
  if (i < e) {
    int s = src[i], d = dst[i];
    int pos = atomicAdd(&cursor[d], 1);
    csr_src[offsets[d] + pos] = s;      // single 4B scatter per edge (was 2 arrays = 2 dirty lines)
  }
}

// ---------------- layer-1 aggregation: agg1 = A @ x   (128 ch, 1 block/node) ----------------
__global__ __launch_bounds__(128) void k_agg1(const float* __restrict__ x, const float* __restrict__ dinv,
                                              const int* __restrict__ deg, const int* __restrict__ offsets,
                                              const int* __restrict__ csr_src,
                                              float* __restrict__ agg, int n) {
  int node = blockIdx.x;
  int c = threadIdx.x;                       // 0..127
  float dn = dinv[node];
  float acc = x[(size_t)node * IN_C + c] * dn * dn;   // self-loop term
  int start = offsets[node];
  int cnt = deg[node] - 1;
  int j = 0;
  for (; j + 4 <= cnt; j += 4) {
    int   s0 = csr_src[start + j    ], s1 = csr_src[start + j + 1];
    int   s2 = csr_src[start + j + 2], s3 = csr_src[start + j + 3];
    float c0 = dinv[s0] * dn, c1 = dinv[s1] * dn;     // broadcast L2-hit loads (dinv = 200 KB)
    float c2 = dinv[s2] * dn, c3 = dinv[s3] * dn;
    float x0 = x[(size_t)s0 * IN_C + c];
    float x1 = x[(size_t)s1 * IN_C + c];
    float x2 = x[(size_t)s2 * IN_C + c];
    float x3 = x[(size_t)s3 * IN_C + c];
    acc += x0 * c0 + x1 * c1 + x2 * c2 + x3 * c3;
  }
  for (; j < cnt; j++) {
    int s = csr_src[start + j];
    acc += x[(size_t)s * IN_C + c] * (dinv[s] * dn);
  }
  agg[(size_t)node * IN_C + c] = acc;
}

// ---------------- GEMM1: h1 = relu(agg1 @ W1 + b1)   (8 nodes/block, 256 thr) ----------------
#define NPB1 8
__global__ __launch_bounds__(256) void k_gemm1(const float* __restrict__ agg, const float* __restrict__ W1,
                                               const float* __restrict__ b1, float* __restrict__ h1, int n) {
  __shared__ float rows[NPB1][IN_C];
  int nb = blockIdx.x * NPB1;
  for (int t = threadIdx.x; t < NPB1 * IN_C; t += 256) {
    int r = t >> 7, k = t & 127;
    int node = nb + r;
    rows[r][k] = (node < n) ? agg[(size_t)node * IN_C + k] : 0.f;
  }
  __syncthreads();
  int c = threadIdx.x;                       // output channel 0..255
  float bias = b1[c];
  float acc[NPB1];
  #pragma unroll
  for (int r = 0; r < NPB1; r++) acc[r] = bias;
  for (int k = 0; k < IN_C; k++) {
    float w = W1[k * H1 + c];                // coalesced; W1 L2-resident, reused x8
    #pragma unroll
    for (int r = 0; r < NPB1; r++) acc[r] += rows[r][k] * w;   // LDS broadcast reads
  }
  #pragma unroll
  for (int r = 0; r < NPB1; r++) {
    int node = nb + r;
    if (node < n) h1[(size_t)node * H1 + c] = fmaxf(acc[r], 0.f);
  }
}

// ---------------- GEMM2: h2 = h1 @ W2   (8 nodes/block, 256 thr = 8x32) ----------------
#define NPB2 8
__global__ __launch_bounds__(256) void k_gemm2(const float* __restrict__ h1, const float* __restrict__ W2,
                                               float* __restrict__ h2, int n) {
  __shared__ float rows[NPB2][H1 + 4];       // +4 pad: r-groups land on distinct banks
  int nb = blockIdx.x * NPB2;
  for (int t = threadIdx.x; t < NPB2 * H1; t += 256) {
    int r = t >> 8, k = t & 255;
    int node = nb + r;
    rows[r][k] = (node < n) ? h1[(size_t)node * H1 + k] : 0.f;
  }
  __syncthreads();
  int r = threadIdx.x >> 5, c = threadIdx.x & 31;
  float acc = 0.f;
  #pragma unroll 4
  for (int k = 0; k < H1; k++) acc += rows[r][k] * W2[k * H2 + c];
  int node = nb + r;
  if (node < n) h2[(size_t)node * H2 + c] = acc;   // bias applied after aggregation
}

// ---------------- layer-2 aggregation: z = A @ h2 + b2   (32 ch, 8 nodes/block) ----------------
__global__ __launch_bounds__(256) void k_agg2(const float* __restrict__ h2, const float* __restrict__ dinv,
                                              const int* __restrict__ deg, const int* __restrict__ offsets,
                                              const int* __restrict__ csr_src,
                                              const float* __restrict__ b2, float* __restrict__ z, int n) {
  int node = blockIdx.x * 8 + (threadIdx.x >> 5);
  int c = threadIdx.x & 31;
  if (node >= n) return;
  float dn = dinv[node];
  float acc = h2[(size_t)node * H2 + c] * dn * dn;
  int start = offsets[node];
  int cnt = deg[node] - 1;
  int j = 0;
  for (; j + 4 <= cnt; j += 4) {
    int   s0 = csr_src[start + j    ], s1 = csr_src[start + j + 1];
    int   s2 = csr_src[start + j + 2], s3 = csr_src[start + j + 3];
    float c0 = dinv[s0] * dn, c1 = dinv[s1] * dn;
    float c2 = dinv[s2] * dn, c3 = dinv[s3] * dn;
    acc += h2[(size_t)s0 * H2 + c] * c0 + h2[(size_t)s1 * H2 + c] * c1
         + h2[(size_t)s2 * H2 + c] * c2 + h2[(size_t)s3 * H2 + c] * c3;
  }
  for (; j < cnt; j++) {
    int s = csr_src[start + j];
    acc += h2[(size_t)s * H2 + c] * (dinv[s] * dn);
  }
  z[(size_t)node * H2 + c] = acc + b2[c];
}

// ---------------- decode: out[p] = dot(z[a], z[b])   (32 lanes/pair) ----------------
__global__ __launch_bounds__(256) void k_decode(const float* __restrict__ z, const int* __restrict__ eli,
                                                float* __restrict__ out, int L) {
  int p = blockIdx.x * 8 + (threadIdx.x >> 5);
  int c = threadIdx.x & 31;
  if (p >= L) return;
  int a = eli[p], b = eli[L + p];
  float v = z[(size_t)a * H2 + c] * z[(size_t)b * H2 + c];
  #pragma unroll
  for (int off = 16; off >= 1; off >>= 1) v += __shfl_xor(v, off, 64);
  if (c == 0) out[p] = v;
}

extern "C" void kernel_launch(void* const* d_in, const int* in_sizes, int n_in,
                              void* d_out, int out_size, void* d_ws, size_t ws_size,
                              hipStream_t stream) {
  const float* x   = (const float*)d_in[0];
  const int*   ei  = (const int*)d_in[1];
  const int*   eli = (const int*)d_in[2];
  const float* W1  = (const float*)d_in[3];
  const float* b1  = (const float*)d_in[4];
  const float* W2  = (const float*)d_in[5];
  const float* b2  = (const float*)d_in[6];
  float* out = (float*)d_out;

  const int N = in_sizes[0] / IN_C;
  const int E = in_sizes[1] / 2;
  const int L = in_sizes[2] / 2;
  const int* e_src = ei;
  const int* e_dst = ei + E;

  // ---- workspace carve (aligned 256B). ----
  char* p = (char*)d_ws;
  auto carve = [&](size_t bytes) -> void* {
    void* r = (void*)p;
    p += (bytes + 255) & ~(size_t)255;
    return r;
  };
  int*   deg      = (int*)  carve((size_t)N * 4);
  int*   cursor   = (int*)  carve((size_t)N * 4);
  float* dinv     = (float*)carve((size_t)N * 4);
  int*   offsets  = (int*)  carve((size_t)N * 4);
  int*   gtotal   = (int*)  carve(256);
  int*   csr_src  = (int*)  carve((size_t)E * 4);
  float* agg1     = (float*)carve((size_t)N * IN_C * 4);  // 25.6 MB; dead after gemm1
  float* h1       = (float*)carve((size_t)N * H1 * 4);    // 51.2 MB
  // alias h2 and z into agg1's space (agg1 no longer needed once gemm1 reads it)
  float* h2 = agg1;                                       // N*32*4 = 6.4 MB
  float* z  = agg1 + (size_t)N * H2;                      // next 6.4 MB

  const int B = 256;
  k_init<<<(N + B - 1) / B, B, 0, stream>>>(deg, cursor, gtotal, N);
  k_deg<<<(E + B - 1) / B, B, 0, stream>>>(e_dst, deg, E);
  k_node_prep<<<(N + B - 1) / B, B, 0, stream>>>(deg, dinv, offsets, gtotal, N);
  k_fill<<<(E + B - 1) / B, B, 0, stream>>>(e_src, e_dst, offsets, cursor, csr_src, E);
  k_agg1<<<N, IN_C, 0, stream>>>(x, dinv, deg, offsets, csr_src, agg1, N);
  k_gemm1<<<(N + NPB1 - 1) / NPB1, 256, 0, stream>>>(agg1, W1, b1, h1, N);
  k_gemm2<<<(N + NPB2 - 1) / NPB2, 256, 0, stream>>>(h1, W2, h2, N);
  k_agg2<<<(N + 7) / 8, 256, 0, stream>>>(h2, dinv, deg, offsets, csr_src, b2, z, N);
  k_decode<<<(L + 7) / 8, 256, 0, stream>>>(z, eli, out, L);
}

// Round 3
// 492.927 us; speedup vs baseline: 1.1240x; 1.1240x over previous
//
#include <hip/hip_runtime.h>

#define IN_C 128
#define H1   256
#define H2   32
#define BWL  8              // bucket width = 256 nodes
#define NBMAX 256           // max buckets (N <= 65536)

// ---------------- init: deg=1 (self-loop), zero bucket counters ----------------
__global__ __launch_bounds__(256) void k_init(int* deg, int* bucket_cnt, int* bucket_cursor, int n, int nb) {
  int i = blockIdx.x * blockDim.x + threadIdx.x;
  if (i < n) deg[i] = 1;
  if (i < nb) { bucket_cnt[i] = 0; bucket_cursor[i] = 0; }
}

// ---------------- degree count + bucket histogram (fused: one pass over dst) ----------------
__global__ __launch_bounds__(256) void k_deg_bin(const int* __restrict__ dst, int* deg,
                                                 int* bucket_cnt, int e, int nb) {
  __shared__ int hist[NBMAX];
  for (int u = threadIdx.x; u < nb; u += 256) hist[u] = 0;
  __syncthreads();
  int base = blockIdx.x * 2048;
  #pragma unroll
  for (int j = 0; j < 8; j++) {
    int i = base + j * 256 + threadIdx.x;
    if (i < e) {
      int d = dst[i];
      atomicAdd(&deg[d], 1);
      atomicAdd(&hist[d >> BWL], 1);
    }
  }
  __syncthreads();
  for (int u = threadIdx.x; u < nb; u += 256) if (hist[u]) atomicAdd(&bucket_cnt[u], hist[u]);
}

// ---------------- scan step 1: per-chunk (2048 elems) exclusive scan of (deg-1); also dinv ----------------
__global__ __launch_bounds__(256) void k_scan_chunk(const int* __restrict__ deg, float* __restrict__ dinv,
                                                    int* __restrict__ loc, int* __restrict__ partials, int n) {
  __shared__ int wsum[4];
  int base = blockIdx.x * 2048;
  int v[8]; int s = 0;
  #pragma unroll
  for (int j = 0; j < 8; j++) {
    int i = base + threadIdx.x * 8 + j;
    int c = 0;
    if (i < n) {
      int dg = deg[i];
      dinv[i] = rsqrtf((float)dg);
      c = dg - 1;
    }
    v[j] = s; s += c;
  }
  int lane = threadIdx.x & 63, wid = threadIdx.x >> 6;
  int val = s;
  #pragma unroll
  for (int off = 1; off < 64; off <<= 1) {
    int t = __shfl_up(val, off, 64);
    if (lane >= off) val += t;
  }
  if (lane == 63) wsum[wid] = val;
  __syncthreads();
  int wp = 0;
  for (int w = 0; w < wid; w++) wp += wsum[w];
  int excl = wp + val - s;      // exclusive prefix of this thread within block
  #pragma unroll
  for (int j = 0; j < 8; j++) {
    int i = base + threadIdx.x * 8 + j;
    if (i < n) loc[i] = excl + v[j];
  }
  if (threadIdx.x == 255) partials[blockIdx.x] = excl + s;   // block total
}

// ---------------- scan step 2 (1 block): scan chunk partials + scan bucket counts ----------------
__global__ __launch_bounds__(256) void k_scan_small(int* partials, int nchunks,
                                                    const int* __restrict__ bucket_cnt,
                                                    int* __restrict__ bucket_base, int nb) {
  __shared__ int tmp[256];
  int t = threadIdx.x;
  int v = (t < nchunks) ? partials[t] : 0;
  tmp[t] = v; __syncthreads();
  for (int off = 1; off < 256; off <<= 1) {
    int x = (t >= off) ? tmp[t - off] : 0;
    __syncthreads();
    tmp[t] += x;
    __syncthreads();
  }
  if (t < nchunks) partials[t] = tmp[t] - v;   // exclusive
  __syncthreads();
  int b = (t < nb) ? bucket_cnt[t] : 0;
  tmp[t] = b; __syncthreads();
  for (int off = 1; off < 256; off <<= 1) {
    int x = (t >= off) ? tmp[t - off] : 0;
    __syncthreads();
    tmp[t] += x;
    __syncthreads();
  }
  if (t < nb) bucket_base[t] = tmp[t] - b;     // exclusive
  if (t == 255) bucket_base[nb] = tmp[255];    // total edges
}

// ---------------- scan step 3: add chunk prefix -> node-ordered CSR offsets ----------------
__global__ __launch_bounds__(256) void k_scan_add(int* __restrict__ loc, const int* __restrict__ partials, int n) {
  int i = blockIdx.x * blockDim.x + threadIdx.x;
  if (i < n) loc[i] += partials[i >> 11];
}

// ---------------- binned partition: (src,dst) packed 8B into bucket-contiguous regions ----------------
__global__ __launch_bounds__(256) void k_scatter(const int* __restrict__ src, const int* __restrict__ dst,
                                                 const int* __restrict__ bucket_base, int* bucket_cursor,
                                                 unsigned long long* __restrict__ binned, int e, int nb) {
  __shared__ int hist[NBMAX];
  __shared__ int wbase[NBMAX];
  int t = threadIdx.x;
  for (int u = t; u < nb; u += 256) hist[u] = 0;
  __syncthreads();
  int base = blockIdx.x * 4096;
  int s_[16], d_[16];
  #pragma unroll
  for (int j = 0; j < 16; j++) {
    int i = base + j * 256 + t;
    if (i < e) {
      s_[j] = src[i]; d_[j] = dst[i];
      atomicAdd(&hist[d_[j] >> BWL], 1);
    } else d_[j] = -1;
  }
  __syncthreads();
  for (int u = t; u < nb; u += 256) {
    int c = hist[u];
    wbase[u] = (c > 0) ? (bucket_base[u] + atomicAdd(&bucket_cursor[u], c)) : 0;
  }
  __syncthreads();
  for (int u = t; u < nb; u += 256) hist[u] = 0;
  __syncthreads();
  #pragma unroll
  for (int j = 0; j < 16; j++) {
    if (d_[j] >= 0) {
      int b = d_[j] >> BWL;
      int r = atomicAdd(&hist[b], 1);
      binned[wbase[b] + r] = ((unsigned long long)(unsigned)d_[j] << 32) | (unsigned)s_[j];
    }
  }
}

// ---------------- CSR fill: one block per bucket; target region ~34KB (L2-resident) ----------------
__global__ __launch_bounds__(256) void k_fill2(const unsigned long long* __restrict__ binned,
                                               const int* __restrict__ bucket_base,
                                               const int* __restrict__ offsets,
                                               int* __restrict__ csr_src, int nb) {
  __shared__ int cur[256];
  int b = blockIdx.x;
  int t = threadIdx.x;
  cur[t] = 0;
  __syncthreads();
  int start = bucket_base[b], end = bucket_base[b + 1];
  int node0 = b << BWL;
  for (int i = start + t; i < end; i += 256) {
    unsigned long long sd = binned[i];
    int s = (int)(sd & 0xffffffffULL), d = (int)(sd >> 32);
    int p = atomicAdd(&cur[d - node0], 1);
    csr_src[offsets[d] + p] = s;
  }
}

// ---------------- layer-1 aggregation: agg1 = A @ x   (128 ch, 1 block/node) ----------------
__global__ __launch_bounds__(128) void k_agg1(const float* __restrict__ x, const float* __restrict__ dinv,
                                              const int* __restrict__ deg, const int* __restrict__ offsets,
                                              const int* __restrict__ csr_src,
                                              float* __restrict__ agg, int n) {
  int node = blockIdx.x;
  int c = threadIdx.x;
  float dn = dinv[node];
  float acc = x[(size_t)node * IN_C + c] * dn * dn;   // self-loop term
  int start = offsets[node];
  int cnt = deg[node] - 1;
  int j = 0;
  for (; j + 4 <= cnt; j += 4) {
    int   s0 = csr_src[start + j    ], s1 = csr_src[start + j + 1];
    int   s2 = csr_src[start + j + 2], s3 = csr_src[start + j + 3];
    float c0 = dinv[s0] * dn, c1 = dinv[s1] * dn;
    float c2 = dinv[s2] * dn, c3 = dinv[s3] * dn;
    float x0 = x[(size_t)s0 * IN_C + c];
    float x1 = x[(size_t)s1 * IN_C + c];
    float x2 = x[(size_t)s2 * IN_C + c];
    float x3 = x[(size_t)s3 * IN_C + c];
    acc += x0 * c0 + x1 * c1 + x2 * c2 + x3 * c3;
  }
  for (; j < cnt; j++) {
    int s = csr_src[start + j];
    acc += x[(size_t)s * IN_C + c] * (dinv[s] * dn);
  }
  agg[(size_t)node * IN_C + c] = acc;
}

// ---------------- GEMM1: h1 = relu(agg1 @ W1 + b1)   (8 nodes/block, 256 thr) ----------------
#define NPB1 8
__global__ __launch_bounds__(256) void k_gemm1(const float* __restrict__ agg, const float* __restrict__ W1,
                                               const float* __restrict__ b1, float* __restrict__ h1, int n) {
  __shared__ float rows[NPB1][IN_C];
  int nb = blockIdx.x * NPB1;
  for (int t = threadIdx.x; t < NPB1 * IN_C; t += 256) {
    int r = t >> 7, k = t & 127;
    int node = nb + r;
    rows[r][k] = (node < n) ? agg[(size_t)node * IN_C + k] : 0.f;
  }
  __syncthreads();
  int c = threadIdx.x;
  float bias = b1[c];
  float acc[NPB1];
  #pragma unroll
  for (int r = 0; r < NPB1; r++) acc[r] = bias;
  for (int k = 0; k < IN_C; k++) {
    float w = W1[k * H1 + c];
    #pragma unroll
    for (int r = 0; r < NPB1; r++) acc[r] += rows[r][k] * w;
  }
  #pragma unroll
  for (int r = 0; r < NPB1; r++) {
    int node = nb + r;
    if (node < n) h1[(size_t)node * H1 + c] = fmaxf(acc[r], 0.f);
  }
}

// ---------------- GEMM2: h2 = h1 @ W2   (8 nodes/block, 256 thr = 8x32) ----------------
#define NPB2 8
__global__ __launch_bounds__(256) void k_gemm2(const float* __restrict__ h1, const float* __restrict__ W2,
                                               float* __restrict__ h2, int n) {
  __shared__ float rows[NPB2][H1 + 4];
  int nb = blockIdx.x * NPB2;
  for (int t = threadIdx.x; t < NPB2 * H1; t += 256) {
    int r = t >> 8, k = t & 255;
    int node = nb + r;
    rows[r][k] = (node < n) ? h1[(size_t)node * H1 + k] : 0.f;
  }
  __syncthreads();
  int r = threadIdx.x >> 5, c = threadIdx.x & 31;
  float acc = 0.f;
  #pragma unroll 4
  for (int k = 0; k < H1; k++) acc += rows[r][k] * W2[k * H2 + c];
  int node = nb + r;
  if (node < n) h2[(size_t)node * H2 + c] = acc;   // bias applied after aggregation
}

// ---------------- layer-2 aggregation: z = A @ h2 + b2 ----------------
__global__ __launch_bounds__(256) void k_agg2(const float* __restrict__ h2, const float* __restrict__ dinv,
                                              const int* __restrict__ deg, const int* __restrict__ offsets,
                                              const int* __restrict__ csr_src,
                                              const float* __restrict__ b2, float* __restrict__ z, int n) {
  int node = blockIdx.x * 8 + (threadIdx.x >> 5);
  int c = threadIdx.x & 31;
  if (node >= n) return;
  float dn = dinv[node];
  float acc = h2[(size_t)node * H2 + c] * dn * dn;
  int start = offsets[node];
  int cnt = deg[node] - 1;
  int j = 0;
  for (; j + 4 <= cnt; j += 4) {
    int   s0 = csr_src[start + j    ], s1 = csr_src[start + j + 1];
    int   s2 = csr_src[start + j + 2], s3 = csr_src[start + j + 3];
    float c0 = dinv[s0] * dn, c1 = dinv[s1] * dn;
    float c2 = dinv[s2] * dn, c3 = dinv[s3] * dn;
    acc += h2[(size_t)s0 * H2 + c] * c0 + h2[(size_t)s1 * H2 + c] * c1
         + h2[(size_t)s2 * H2 + c] * c2 + h2[(size_t)s3 * H2 + c] * c3;
  }
  for (; j < cnt; j++) {
    int s = csr_src[start + j];
    acc += h2[(size_t)s * H2 + c] * (dinv[s] * dn);
  }
  z[(size_t)node * H2 + c] = acc + b2[c];
}

// ---------------- decode: out[p] = dot(z[a], z[b]) ----------------
__global__ __launch_bounds__(256) void k_decode(const float* __restrict__ z, const int* __restrict__ eli,
                                                float* __restrict__ out, int L) {
  int p = blockIdx.x * 8 + (threadIdx.x >> 5);
  int c = threadIdx.x & 31;
  if (p >= L) return;
  int a = eli[p], b = eli[L + p];
  float v = z[(size_t)a * H2 + c] * z[(size_t)b * H2 + c];
  #pragma unroll
  for (int off = 16; off >= 1; off >>= 1) v += __shfl_xor(v, off, 64);
  if (c == 0) out[p] = v;
}

extern "C" void kernel_launch(void* const* d_in, const int* in_sizes, int n_in,
                              void* d_out, int out_size, void* d_ws, size_t ws_size,
                              hipStream_t stream) {
  const float* x   = (const float*)d_in[0];
  const int*   ei  = (const int*)d_in[1];
  const int*   eli = (const int*)d_in[2];
  const float* W1  = (const float*)d_in[3];
  const float* b1  = (const float*)d_in[4];
  const float* W2  = (const float*)d_in[5];
  const float* b2  = (const float*)d_in[6];
  float* out = (float*)d_out;

  const int N = in_sizes[0] / IN_C;
  const int E = in_sizes[1] / 2;
  const int L = in_sizes[2] / 2;
  const int* e_src = ei;
  const int* e_dst = ei + E;
  const int NB = (N + 255) >> BWL;            // 196 buckets for N=50000
  const int NCHUNK = (N + 2047) >> 11;        // 25 scan chunks

  // ---- workspace carve (aligned 256B). ----
  char* p = (char*)d_ws;
  auto carve = [&](size_t bytes) -> void* {
    void* r = (void*)p;
    p += (bytes + 255) & ~(size_t)255;
    return r;
  };
  int*   deg       = (int*)  carve((size_t)N * 4);
  float* dinv      = (float*)carve((size_t)N * 4);
  int*   offsets   = (int*)  carve((size_t)N * 4);     // loc -> offsets in place
  int*   partials  = (int*)  carve(256 * 4);
  int*   bcnt      = (int*)  carve(NBMAX * 4);
  int*   bbase     = (int*)  carve((NBMAX + 1) * 4);
  int*   bcursor   = (int*)  carve(NBMAX * 4);
  int*   csr_src   = (int*)  carve((size_t)E * 4);     // 6.4 MB
  float* agg1      = (float*)carve((size_t)N * IN_C * 4);  // 25.6 MB; dead after gemm1
  float* h1        = (float*)carve((size_t)N * H1 * 4);    // 51.2 MB
  // aliases: binned (12.8 MB) lives in h1's space (dead before gemm1 writes h1);
  // h2 and z live in agg1's space (dead after gemm1 reads it)
  unsigned long long* binned = (unsigned long long*)h1;
  float* h2 = agg1;
  float* z  = agg1 + (size_t)N * H2;

  const int B = 256;
  k_init<<<(N + B - 1) / B, B, 0, stream>>>(deg, bcnt, bcursor, N, NB);
  k_deg_bin<<<(E + 2047) / 2048, B, 0, stream>>>(e_dst, deg, bcnt, E, NB);
  k_scan_chunk<<<NCHUNK, B, 0, stream>>>(deg, dinv, offsets, partials, N);
  k_scan_small<<<1, B, 0, stream>>>(partials, NCHUNK, bcnt, bbase, NB);
  k_scan_add<<<(N + B - 1) / B, B, 0, stream>>>(offsets, partials, N);
  k_scatter<<<(E + 4095) / 4096, B, 0, stream>>>(e_src, e_dst, bbase, bcursor, binned, E, NB);
  k_fill2<<<NB, B, 0, stream>>>(binned, bbase, offsets, csr_src, NB);
  k_agg1<<<N, IN_C, 0, stream>>>(x, dinv, deg, offsets, csr_src, agg1, N);
  k_gemm1<<<(N + NPB1 - 1) / NPB1, B, 0, stream>>>(agg1, W1, b1, h1, N);
  k_gemm2<<<(N + NPB2 - 1) / NPB2, B, 0, stream>>>(h1, W2, h2, N);
  k_agg2<<<(N + 7) / 8, B, 0, stream>>>(h2, dinv, deg, offsets, csr_src, b2, z, N);
  k_decode<<<(L + 7) / 8, B, 0, stream>>>(z, eli, out, L);
}

// Round 4
// 433.916 us; speedup vs baseline: 1.2769x; 1.1360x over previous
//
#include <hip/hip_runtime.h>
#include <hip/hip_fp16.h>

#define IN_C 128
#define H1   256
#define H2   32
#define BWL  8              // bucket width = 256 nodes
#define NBMAX 256           // max buckets (N <= 65536)

// ---------------- init: deg=1 (self-loop), zero bucket counters ----------------
__global__ __launch_bounds__(256) void k_init(int* deg, int* bucket_cnt, int* bucket_cursor, int n, int nb) {
  int i = blockIdx.x * blockDim.x + threadIdx.x;
  if (i < n) deg[i] = 1;
  if (i < nb) { bucket_cnt[i] = 0; bucket_cursor[i] = 0; }
}

// ---------------- cast x (f32) -> xh (fp16), vectorized ----------------
__global__ __launch_bounds__(256) void k_cast(const float4* __restrict__ x4, __half2* __restrict__ xh, int n4) {
  int i = blockIdx.x * 256 + threadIdx.x;
  if (i < n4) {
    float4 v = x4[i];
    xh[2 * i]     = __floats2half2_rn(v.x, v.y);
    xh[2 * i + 1] = __floats2half2_rn(v.z, v.w);
  }
}

// ---------------- degree count + bucket histogram ----------------
__global__ __launch_bounds__(256) void k_deg_bin(const int* __restrict__ dst, int* deg,
                                                 int* bucket_cnt, int e, int nb) {
  __shared__ int hist[NBMAX];
  for (int u = threadIdx.x; u < nb; u += 256) hist[u] = 0;
  __syncthreads();
  int base = blockIdx.x * 2048;
  #pragma unroll
  for (int j = 0; j < 8; j++) {
    int i = base + j * 256 + threadIdx.x;
    if (i < e) {
      int d = dst[i];
      atomicAdd(&deg[d], 1);
      atomicAdd(&hist[d >> BWL], 1);
    }
  }
  __syncthreads();
  for (int u = threadIdx.x; u < nb; u += 256) if (hist[u]) atomicAdd(&bucket_cnt[u], hist[u]);
}

// ---------------- scan step 1: per-chunk (2048) exclusive scan of (deg-1); also dinv ----------------
__global__ __launch_bounds__(256) void k_scan_chunk(const int* __restrict__ deg, float* __restrict__ dinv,
                                                    int* __restrict__ loc, int* __restrict__ partials, int n) {
  __shared__ int wsum[4];
  int base = blockIdx.x * 2048;
  int v[8]; int s = 0;
  #pragma unroll
  for (int j = 0; j < 8; j++) {
    int i = base + threadIdx.x * 8 + j;
    int c = 0;
    if (i < n) {
      int dg = deg[i];
      dinv[i] = rsqrtf((float)dg);
      c = dg - 1;
    }
    v[j] = s; s += c;
  }
  int lane = threadIdx.x & 63, wid = threadIdx.x >> 6;
  int val = s;
  #pragma unroll
  for (int off = 1; off < 64; off <<= 1) {
    int t = __shfl_up(val, off, 64);
    if (lane >= off) val += t;
  }
  if (lane == 63) wsum[wid] = val;
  __syncthreads();
  int wp = 0;
  for (int w = 0; w < wid; w++) wp += wsum[w];
  int excl = wp + val - s;
  #pragma unroll
  for (int j = 0; j < 8; j++) {
    int i = base + threadIdx.x * 8 + j;
    if (i < n) loc[i] = excl + v[j];
  }
  if (threadIdx.x == 255) partials[blockIdx.x] = excl + s;
}

// ---------------- scan step 2 (1 block): scan chunk partials + bucket counts ----------------
__global__ __launch_bounds__(256) void k_scan_small(int* partials, int nchunks,
                                                    const int* __restrict__ bucket_cnt,
                                                    int* __restrict__ bucket_base, int nb) {
  __shared__ int tmp[256];
  int t = threadIdx.x;
  int v = (t < nchunks) ? partials[t] : 0;
  tmp[t] = v; __syncthreads();
  for (int off = 1; off < 256; off <<= 1) {
    int x = (t >= off) ? tmp[t - off] : 0;
    __syncthreads();
    tmp[t] += x;
    __syncthreads();
  }
  if (t < nchunks) partials[t] = tmp[t] - v;
  __syncthreads();
  int b = (t < nb) ? bucket_cnt[t] : 0;
  tmp[t] = b; __syncthreads();
  for (int off = 1; off < 256; off <<= 1) {
    int x = (t >= off) ? tmp[t - off] : 0;
    __syncthreads();
    tmp[t] += x;
    __syncthreads();
  }
  if (t < nb) bucket_base[t] = tmp[t] - b;
  if (t == 255) bucket_base[nb] = tmp[255];
}

// ---------------- scan step 3: add chunk prefix ----------------
__global__ __launch_bounds__(256) void k_scan_add(int* __restrict__ loc, const int* __restrict__ partials, int n) {
  int i = blockIdx.x * blockDim.x + threadIdx.x;
  if (i < n) loc[i] += partials[i >> 11];
}

// ---------------- binned partition: (src,dst) packed 8B ----------------
__global__ __launch_bounds__(256) void k_scatter(const int* __restrict__ src, const int* __restrict__ dst,
                                                 const int* __restrict__ bucket_base, int* bucket_cursor,
                                                 unsigned long long* __restrict__ binned, int e, int nb) {
  __shared__ int hist[NBMAX];
  __shared__ int wbase[NBMAX];
  int t = threadIdx.x;
  for (int u = t; u < nb; u += 256) hist[u] = 0;
  __syncthreads();
  int base = blockIdx.x * 4096;
  int s_[16], d_[16];
  #pragma unroll
  for (int j = 0; j < 16; j++) {
    int i = base + j * 256 + t;
    if (i < e) {
      s_[j] = src[i]; d_[j] = dst[i];
      atomicAdd(&hist[d_[j] >> BWL], 1);
    } else d_[j] = -1;
  }
  __syncthreads();
  for (int u = t; u < nb; u += 256) {
    int c = hist[u];
    wbase[u] = (c > 0) ? (bucket_base[u] + atomicAdd(&bucket_cursor[u], c)) : 0;
  }
  __syncthreads();
  for (int u = t; u < nb; u += 256) hist[u] = 0;
  __syncthreads();
  #pragma unroll
  for (int j = 0; j < 16; j++) {
    if (d_[j] >= 0) {
      int b = d_[j] >> BWL;
      int r = atomicAdd(&hist[b], 1);
      binned[wbase[b] + r] = ((unsigned long long)(unsigned)d_[j] << 32) | (unsigned)s_[j];
    }
  }
}

// ---------------- CSR fill: one block per bucket ----------------
__global__ __launch_bounds__(256) void k_fill2(const unsigned long long* __restrict__ binned,
                                               const int* __restrict__ bucket_base,
                                               const int* __restrict__ offsets,
                                               int* __restrict__ csr_src, int nb) {
  __shared__ int cur[256];
  int b = blockIdx.x;
  int t = threadIdx.x;
  cur[t] = 0;
  __syncthreads();
  int start = bucket_base[b], end = bucket_base[b + 1];
  int node0 = b << BWL;
  for (int i = start + t; i < end; i += 256) {
    unsigned long long sd = binned[i];
    int s = (int)(sd & 0xffffffffULL), d = (int)(sd >> 32);
    int p = atomicAdd(&cur[d - node0], 1);
    csr_src[offsets[d] + p] = s;
  }
}

// ---------------- layer-1 aggregation: one wave/node, half2 lanes ----------------
__global__ __launch_bounds__(256) void k_agg1(const __half2* __restrict__ xh, const float* __restrict__ dinv,
                                              const int* __restrict__ deg, const int* __restrict__ offsets,
                                              const int* __restrict__ csr_src,
                                              __half2* __restrict__ aggh, int n) {
  int node = blockIdx.x * 4 + (threadIdx.x >> 6);
  int lane = threadIdx.x & 63;                 // half2 index 0..63 (128 ch)
  if (node >= n) return;
  float dn = dinv[node];
  float2 self = __half22float2(xh[(size_t)node * 64 + lane]);
  float a0 = self.x * dn * dn, a1 = self.y * dn * dn;
  int start = offsets[node];
  int cnt = deg[node] - 1;
  int j = 0;
  for (; j + 4 <= cnt; j += 4) {
    int   s0 = csr_src[start + j    ], s1 = csr_src[start + j + 1];
    int   s2 = csr_src[start + j + 2], s3 = csr_src[start + j + 3];
    float c0 = dinv[s0] * dn, c1 = dinv[s1] * dn;    // broadcast L2-hit loads
    float c2 = dinv[s2] * dn, c3 = dinv[s3] * dn;
    float2 v0 = __half22float2(xh[(size_t)s0 * 64 + lane]);
    float2 v1 = __half22float2(xh[(size_t)s1 * 64 + lane]);
    float2 v2 = __half22float2(xh[(size_t)s2 * 64 + lane]);
    float2 v3 = __half22float2(xh[(size_t)s3 * 64 + lane]);
    a0 += v0.x * c0 + v1.x * c1 + v2.x * c2 + v3.x * c3;
    a1 += v0.y * c0 + v1.y * c1 + v2.y * c2 + v3.y * c3;
  }
  for (; j < cnt; j++) {
    int s = csr_src[start + j];
    float c = dinv[s] * dn;
    float2 v = __half22float2(xh[(size_t)s * 64 + lane]);
    a0 += v.x * c; a1 += v.y * c;
  }
  aggh[(size_t)node * 64 + lane] = __floats2half2_rn(a0, a1);
}

// ---------------- GEMM1: h1 = relu(agg1 @ W1 + b1)  (8 nodes/block, 256 thr, f32 math) ----------------
#define NPB1 8
__global__ __launch_bounds__(256) void k_gemm1(const __half2* __restrict__ aggh, const float* __restrict__ W1,
                                               const float* __restrict__ b1, __half* __restrict__ h1h, int n) {
  __shared__ float rows[NPB1][IN_C];
  int nb = blockIdx.x * NPB1;
  for (int t = threadIdx.x; t < NPB1 * 64; t += 256) {
    int r = t >> 6, k2 = t & 63;
    int node = nb + r;
    float2 v = (node < n) ? __half22float2(aggh[(size_t)node * 64 + k2]) : make_float2(0.f, 0.f);
    rows[r][2 * k2] = v.x; rows[r][2 * k2 + 1] = v.y;
  }
  __syncthreads();
  int c = threadIdx.x;
  float bias = b1[c];
  float acc[NPB1];
  #pragma unroll
  for (int r = 0; r < NPB1; r++) acc[r] = bias;
  for (int k = 0; k < IN_C; k++) {
    float w = W1[k * H1 + c];
    #pragma unroll
    for (int r = 0; r < NPB1; r++) acc[r] += rows[r][k] * w;   // LDS broadcast reads
  }
  #pragma unroll
  for (int r = 0; r < NPB1; r++) {
    int node = nb + r;
    if (node < n) h1h[(size_t)node * H1 + c] = __float2half(fmaxf(acc[r], 0.f));
  }
}

// ---------------- GEMM2: h2 = h1 @ W2  (8 nodes/block, 256 thr = 8x32) ----------------
#define NPB2 8
__global__ __launch_bounds__(256) void k_gemm2(const __half2* __restrict__ h1h2, const float* __restrict__ W2,
                                               __half* __restrict__ h2h, int n) {
  __shared__ float rows[NPB2][H1 + 4];
  int nb = blockIdx.x * NPB2;
  for (int t = threadIdx.x; t < NPB2 * 128; t += 256) {
    int r = t >> 7, k2 = t & 127;
    int node = nb + r;
    float2 v = (node < n) ? __half22float2(h1h2[(size_t)node * 128 + k2]) : make_float2(0.f, 0.f);
    rows[r][2 * k2] = v.x; rows[r][2 * k2 + 1] = v.y;
  }
  __syncthreads();
  int r = threadIdx.x >> 5, c = threadIdx.x & 31;
  float acc = 0.f;
  #pragma unroll 4
  for (int k = 0; k < H1; k++) acc += rows[r][k] * W2[k * H2 + c];
  int node = nb + r;
  if (node < n) h2h[(size_t)node * H2 + c] = __float2half(acc);  // bias after aggregation
}

// ---------------- layer-2 aggregation: z = A @ h2 + b2  (16 lanes/node, half2) ----------------
__global__ __launch_bounds__(256) void k_agg2(const __half2* __restrict__ h2h2, const float* __restrict__ dinv,
                                              const int* __restrict__ deg, const int* __restrict__ offsets,
                                              const int* __restrict__ csr_src,
                                              const float* __restrict__ b2, __half2* __restrict__ zh2, int n) {
  int node = blockIdx.x * 16 + (threadIdx.x >> 4);
  int c2 = threadIdx.x & 15;                   // half2 index 0..15 (32 ch)
  if (node >= n) return;
  float dn = dinv[node];
  float2 self = __half22float2(h2h2[(size_t)node * 16 + c2]);
  float a0 = self.x * dn * dn, a1 = self.y * dn * dn;
  int start = offsets[node];
  int cnt = deg[node] - 1;
  int j = 0;
  for (; j + 4 <= cnt; j += 4) {
    int   s0 = csr_src[start + j    ], s1 = csr_src[start + j + 1];
    int   s2 = csr_src[start + j + 2], s3 = csr_src[start + j + 3];
    float c0 = dinv[s0] * dn, c1 = dinv[s1] * dn;
    float c2f = dinv[s2] * dn, c3 = dinv[s3] * dn;
    float2 v0 = __half22float2(h2h2[(size_t)s0 * 16 + c2]);
    float2 v1 = __half22float2(h2h2[(size_t)s1 * 16 + c2]);
    float2 v2 = __half22float2(h2h2[(size_t)s2 * 16 + c2]);
    float2 v3 = __half22float2(h2h2[(size_t)s3 * 16 + c2]);
    a0 += v0.x * c0 + v1.x * c1 + v2.x * c2f + v3.x * c3;
    a1 += v0.y * c0 + v1.y * c1 + v2.y * c2f + v3.y * c3;
  }
  for (; j < cnt; j++) {
    int s = csr_src[start + j];
    float c = dinv[s] * dn;
    float2 v = __half22float2(h2h2[(size_t)s * 16 + c2]);
    a0 += v.x * c; a1 += v.y * c;
  }
  zh2[(size_t)node * 16 + c2] = __floats2half2_rn(a0 + b2[2 * c2], a1 + b2[2 * c2 + 1]);
}

// ---------------- decode: out[p] = dot(z[a], z[b])  (16 lanes/pair, half2) ----------------
__global__ __launch_bounds__(256) void k_decode(const __half2* __restrict__ zh2, const int* __restrict__ eli,
                                                float* __restrict__ out, int L) {
  int p = blockIdx.x * 16 + (threadIdx.x >> 4);
  int c2 = threadIdx.x & 15;
  if (p >= L) return;
  int a = eli[p], b = eli[L + p];
  float2 va = __half22float2(zh2[(size_t)a * 16 + c2]);
  float2 vb = __half22float2(zh2[(size_t)b * 16 + c2]);
  float v = va.x * vb.x + va.y * vb.y;
  #pragma unroll
  for (int off = 8; off >= 1; off >>= 1) v += __shfl_xor(v, off, 64);  // stays within 16-lane group
  if (c2 == 0) out[p] = v;
}

extern "C" void kernel_launch(void* const* d_in, const int* in_sizes, int n_in,
                              void* d_out, int out_size, void* d_ws, size_t ws_size,
                              hipStream_t stream) {
  const float* x   = (const float*)d_in[0];
  const int*   ei  = (const int*)d_in[1];
  const int*   eli = (const int*)d_in[2];
  const float* W1  = (const float*)d_in[3];
  const float* b1  = (const float*)d_in[4];
  const float* W2  = (const float*)d_in[5];
  const float* b2  = (const float*)d_in[6];
  float* out = (float*)d_out;

  const int N = in_sizes[0] / IN_C;
  const int E = in_sizes[1] / 2;
  const int L = in_sizes[2] / 2;
  const int* e_src = ei;
  const int* e_dst = ei + E;
  const int NB = (N + 255) >> BWL;
  const int NCHUNK = (N + 2047) >> 11;

  char* p = (char*)d_ws;
  auto carve = [&](size_t bytes) -> void* {
    void* r = (void*)p;
    p += (bytes + 255) & ~(size_t)255;
    return r;
  };
  int*   deg       = (int*)  carve((size_t)N * 4);
  float* dinv      = (float*)carve((size_t)N * 4);
  int*   offsets   = (int*)  carve((size_t)N * 4);
  int*   partials  = (int*)  carve(256 * 4);
  int*   bcnt      = (int*)  carve(NBMAX * 4);
  int*   bbase     = (int*)  carve((NBMAX + 1) * 4);
  int*   bcursor   = (int*)  carve(NBMAX * 4);
  int*   csr_src   = (int*)  carve((size_t)E * 4);            // 6.4 MB
  __half2* xh      = (__half2*)carve((size_t)N * IN_C * 2);   // 12.8 MB
  __half2* aggh    = (__half2*)carve((size_t)N * IN_C * 2);   // 12.8 MB; dead after gemm1
  __half*  h1h     = (__half*) carve((size_t)N * H1 * 2);     // 25.6 MB
  // aliases: binned (12.8 MB) in h1h space (dead before gemm1 writes h1h);
  // h2 and z in aggh space (dead after gemm1 reads it)
  unsigned long long* binned = (unsigned long long*)h1h;
  __half*  h2h = (__half*)aggh;
  __half2* h2h2 = (__half2*)aggh;
  __half2* zh2 = (__half2*)((char*)aggh + (size_t)N * H2 * 2);

  const int B = 256;
  k_init<<<(N + B - 1) / B, B, 0, stream>>>(deg, bcnt, bcursor, N, NB);
  k_cast<<<(N * IN_C / 4 + B - 1) / B, B, 0, stream>>>((const float4*)x, xh, N * IN_C / 4);
  k_deg_bin<<<(E + 2047) / 2048, B, 0, stream>>>(e_dst, deg, bcnt, E, NB);
  k_scan_chunk<<<NCHUNK, B, 0, stream>>>(deg, dinv, offsets, partials, N);
  k_scan_small<<<1, B, 0, stream>>>(partials, NCHUNK, bcnt, bbase, NB);
  k_scan_add<<<(N + B - 1) / B, B, 0, stream>>>(offsets, partials, N);
  k_scatter<<<(E + 4095) / 4096, B, 0, stream>>>(e_src, e_dst, bbase, bcursor, binned, E, NB);
  k_fill2<<<NB, B, 0, stream>>>(binned, bbase, offsets, csr_src, NB);
  k_agg1<<<(N + 3) / 4, B, 0, stream>>>(xh, dinv, deg, offsets, csr_src, aggh, N);
  k_gemm1<<<(N + NPB1 - 1) / NPB1, B, 0, stream>>>(aggh, W1, b1, h1h, N);
  k_gemm2<<<(N + NPB2 - 1) / NPB2, B, 0, stream>>>((const __half2*)h1h, W2, h2h, N);
  k_agg2<<<(N + 15) / 16, B, 0, stream>>>(h2h2, dinv, deg, offsets, csr_src, b2, zh2, N);
  k_decode<<<(L + 15) / 16, B, 0, stream>>>(zh2, eli, out, L);
}

// Round 5
// 370.766 us; speedup vs baseline: 1.4944x; 1.1703x over previous
//
#include <hip/hip_runtime.h>
#include <hip/hip_fp16.h>

#define IN_C 128
#define H1   256
#define H2   32
#define BWL  8              // bucket width = 256 nodes
#define NBMAX 256           // max buckets (N <= 65536)

// ---------------- init: zero bucket counters ----------------
__global__ __launch_bounds__(256) void k_init(int* bucket_cnt, int* bucket_cursor, int nb) {
  int i = blockIdx.x * blockDim.x + threadIdx.x;
  if (i < nb) { bucket_cnt[i] = 0; bucket_cursor[i] = 0; }
}

// ---------------- cast x (f32) -> xh (fp16), vectorized ----------------
__global__ __launch_bounds__(256) void k_cast(const float4* __restrict__ x4, __half2* __restrict__ xh, int n4) {
  int i = blockIdx.x * 256 + threadIdx.x;
  if (i < n4) {
    float4 v = x4[i];
    xh[2 * i]     = __floats2half2_rn(v.x, v.y);
    xh[2 * i + 1] = __floats2half2_rn(v.z, v.w);
  }
}

// ---------------- bucket histogram only (NO global per-node atomics) ----------------
__global__ __launch_bounds__(256) void k_bin(const int* __restrict__ dst, int* bucket_cnt, int e, int nb) {
  __shared__ int hist[NBMAX];
  for (int u = threadIdx.x; u < nb; u += 256) hist[u] = 0;
  __syncthreads();
  int base = blockIdx.x * 2048;
  #pragma unroll
  for (int j = 0; j < 8; j++) {
    int i = base + j * 256 + threadIdx.x;
    if (i < e) atomicAdd(&hist[dst[i] >> BWL], 1);
  }
  __syncthreads();
  for (int u = threadIdx.x; u < nb; u += 256) if (hist[u]) atomicAdd(&bucket_cnt[u], hist[u]);
}

// ---------------- scan bucket counts -> bucket_base (1 block) ----------------
__global__ __launch_bounds__(256) void k_scan_bkt(const int* __restrict__ bucket_cnt,
                                                  int* __restrict__ bucket_base, int nb) {
  __shared__ int tmp[256];
  int t = threadIdx.x;
  int b = (t < nb) ? bucket_cnt[t] : 0;
  tmp[t] = b; __syncthreads();
  for (int off = 1; off < 256; off <<= 1) {
    int x = (t >= off) ? tmp[t - off] : 0;
    __syncthreads();
    tmp[t] += x;
    __syncthreads();
  }
  if (t < nb) bucket_base[t] = tmp[t] - b;
  if (t == 255) bucket_base[nb] = tmp[255];
}

// ---------------- binned partition: (src,dst) packed 8B ----------------
__global__ __launch_bounds__(256) void k_scatter(const int* __restrict__ src, const int* __restrict__ dst,
                                                 const int* __restrict__ bucket_base, int* bucket_cursor,
                                                 unsigned long long* __restrict__ binned, int e, int nb) {
  __shared__ int hist[NBMAX];
  __shared__ int wbase[NBMAX];
  int t = threadIdx.x;
  for (int u = t; u < nb; u += 256) hist[u] = 0;
  __syncthreads();
  int base = blockIdx.x * 4096;
  int s_[16], d_[16];
  #pragma unroll
  for (int j = 0; j < 16; j++) {
    int i = base + j * 256 + t;
    if (i < e) {
      s_[j] = src[i]; d_[j] = dst[i];
      atomicAdd(&hist[d_[j] >> BWL], 1);
    } else d_[j] = -1;
  }
  __syncthreads();
  for (int u = t; u < nb; u += 256) {
    int c = hist[u];
    wbase[u] = (c > 0) ? (bucket_base[u] + atomicAdd(&bucket_cursor[u], c)) : 0;
  }
  __syncthreads();
  for (int u = t; u < nb; u += 256) hist[u] = 0;
  __syncthreads();
  #pragma unroll
  for (int j = 0; j < 16; j++) {
    if (d_[j] >= 0) {
      int b = d_[j] >> BWL;
      int r = atomicAdd(&hist[b], 1);
      binned[wbase[b] + r] = ((unsigned long long)(unsigned)d_[j] << 32) | (unsigned)s_[j];
    }
  }
}

// ---------------- CSR fill: one block/bucket. LDS degree count + prefix -> offsets/ecnt/dinv, place edges ----------------
__global__ __launch_bounds__(256) void k_fill2(const unsigned long long* __restrict__ binned,
                                               const int* __restrict__ bucket_base,
                                               int* __restrict__ csr_src,
                                               int* __restrict__ offsets, int* __restrict__ ecnt,
                                               float* __restrict__ dinv, int n, int nb) {
  __shared__ int cnt[256], pre[256], cur[256], loc[256];
  int b = blockIdx.x;
  int t = threadIdx.x;
  cnt[t] = 0; cur[t] = 0;
  __syncthreads();
  int start = bucket_base[b], end = bucket_base[b + 1];
  int node0 = b << BWL;
  // pass 1: per-node degree count (bucket region ~64KB, L2-hot)
  for (int i = start + t; i < end; i += 256) {
    int d = (int)(binned[i] >> 32);
    atomicAdd(&cnt[d - node0], 1);
  }
  __syncthreads();
  // exclusive prefix scan of cnt
  int v = cnt[t];
  pre[t] = v; __syncthreads();
  for (int off = 1; off < 256; off <<= 1) {
    int x = (t >= off) ? pre[t - off] : 0;
    __syncthreads();
    pre[t] += x;
    __syncthreads();
  }
  int excl = pre[t] - v;
  loc[t] = excl;
  int node = node0 + t;
  if (node < n) {
    offsets[node] = start + excl;
    ecnt[node] = v;                       // real-edge count (self-loop handled analytically)
    dinv[node] = rsqrtf((float)(v + 1));
  }
  __syncthreads();
  // pass 2: place edges
  for (int i = start + t; i < end; i += 256) {
    unsigned long long sd = binned[i];
    int s = (int)(sd & 0xffffffffULL), d = (int)(sd >> 32);
    int li = d - node0;
    int p = atomicAdd(&cur[li], 1);
    csr_src[start + loc[li] + p] = s;
  }
}

// ---------------- layer-1 aggregation: one wave/node, half2 lanes ----------------
__global__ __launch_bounds__(256) void k_agg1(const __half2* __restrict__ xh, const float* __restrict__ dinv,
                                              const int* __restrict__ ecnt, const int* __restrict__ offsets,
                                              const int* __restrict__ csr_src,
                                              __half2* __restrict__ aggh, int n) {
  int node = blockIdx.x * 4 + (threadIdx.x >> 6);
  int lane = threadIdx.x & 63;                 // half2 index 0..63 (128 ch)
  if (node >= n) return;
  float dn = dinv[node];
  float2 self = __half22float2(xh[(size_t)node * 64 + lane]);
  float a0 = self.x * dn * dn, a1 = self.y * dn * dn;
  int start = offsets[node];
  int cnt = ecnt[node];
  int j = 0;
  for (; j + 4 <= cnt; j += 4) {
    int   s0 = csr_src[start + j    ], s1 = csr_src[start + j + 1];
    int   s2 = csr_src[start + j + 2], s3 = csr_src[start + j + 3];
    float c0 = dinv[s0] * dn, c1 = dinv[s1] * dn;    // broadcast L2-hit loads
    float c2 = dinv[s2] * dn, c3 = dinv[s3] * dn;
    float2 v0 = __half22float2(xh[(size_t)s0 * 64 + lane]);
    float2 v1 = __half22float2(xh[(size_t)s1 * 64 + lane]);
    float2 v2 = __half22float2(xh[(size_t)s2 * 64 + lane]);
    float2 v3 = __half22float2(xh[(size_t)s3 * 64 + lane]);
    a0 += v0.x * c0 + v1.x * c1 + v2.x * c2 + v3.x * c3;
    a1 += v0.y * c0 + v1.y * c1 + v2.y * c2 + v3.y * c3;
  }
  for (; j < cnt; j++) {
    int s = csr_src[start + j];
    float c = dinv[s] * dn;
    float2 v = __half22float2(xh[(size_t)s * 64 + lane]);
    a0 += v.x * c; a1 += v.y * c;
  }
  aggh[(size_t)node * 64 + lane] = __floats2half2_rn(a0, a1);
}

// ---------------- GEMM1: h1 = relu(agg1 @ W1 + b1)  (8 nodes/block, 256 thr, f32 math) ----------------
#define NPB1 8
__global__ __launch_bounds__(256) void k_gemm1(const __half2* __restrict__ aggh, const float* __restrict__ W1,
                                               const float* __restrict__ b1, __half* __restrict__ h1h, int n) {
  __shared__ float rows[NPB1][IN_C];
  int nb = blockIdx.x * NPB1;
  for (int t = threadIdx.x; t < NPB1 * 64; t += 256) {
    int r = t >> 6, k2 = t & 63;
    int node = nb + r;
    float2 v = (node < n) ? __half22float2(aggh[(size_t)node * 64 + k2]) : make_float2(0.f, 0.f);
    rows[r][2 * k2] = v.x; rows[r][2 * k2 + 1] = v.y;
  }
  __syncthreads();
  int c = threadIdx.x;
  float bias = b1[c];
  float acc[NPB1];
  #pragma unroll
  for (int r = 0; r < NPB1; r++) acc[r] = bias;
  for (int k = 0; k < IN_C; k++) {
    float w = W1[k * H1 + c];
    #pragma unroll
    for (int r = 0; r < NPB1; r++) acc[r] += rows[r][k] * w;   // LDS broadcast reads
  }
  #pragma unroll
  for (int r = 0; r < NPB1; r++) {
    int node = nb + r;
    if (node < n) h1h[(size_t)node * H1 + c] = __float2half(fmaxf(acc[r], 0.f));
  }
}

// ---------------- GEMM2: h2 = h1 @ W2  (8 nodes/block, 256 thr = 8x32) ----------------
#define NPB2 8
__global__ __launch_bounds__(256) void k_gemm2(const __half2* __restrict__ h1h2, const float* __restrict__ W2,
                                               __half* __restrict__ h2h, int n) {
  __shared__ float rows[NPB2][H1 + 4];
  int nb = blockIdx.x * NPB2;
  for (int t = threadIdx.x; t < NPB2 * 128; t += 256) {
    int r = t >> 7, k2 = t & 127;
    int node = nb + r;
    float2 v = (node < n) ? __half22float2(h1h2[(size_t)node * 128 + k2]) : make_float2(0.f, 0.f);
    rows[r][2 * k2] = v.x; rows[r][2 * k2 + 1] = v.y;
  }
  __syncthreads();
  int r = threadIdx.x >> 5, c = threadIdx.x & 31;
  float acc = 0.f;
  #pragma unroll 4
  for (int k = 0; k < H1; k++) acc += rows[r][k] * W2[k * H2 + c];
  int node = nb + r;
  if (node < n) h2h[(size_t)node * H2 + c] = __float2half(acc);  // bias after aggregation
}

// ---------------- layer-2 aggregation: z = A @ h2 + b2  (16 lanes/node, half2) ----------------
__global__ __launch_bounds__(256) void k_agg2(const __half2* __restrict__ h2h2, const float* __restrict__ dinv,
                                              const int* __restrict__ ecnt, const int* __restrict__ offsets,
                                              const int* __restrict__ csr_src,
                                              const float* __restrict__ b2, __half2* __restrict__ zh2, int n) {
  int node = blockIdx.x * 16 + (threadIdx.x >> 4);
  int c2 = threadIdx.x & 15;                   // half2 index 0..15 (32 ch)
  if (node >= n) return;
  float dn = dinv[node];
  float2 self = __half22float2(h2h2[(size_t)node * 16 + c2]);
  float a0 = self.x * dn * dn, a1 = self.y * dn * dn;
  int start = offsets[node];
  int cnt = ecnt[node];
  int j = 0;
  for (; j + 4 <= cnt; j += 4) {
    int   s0 = csr_src[start + j    ], s1 = csr_src[start + j + 1];
    int   s2 = csr_src[start + j + 2], s3 = csr_src[start + j + 3];
    float c0 = dinv[s0] * dn, c1 = dinv[s1] * dn;
    float c2f = dinv[s2] * dn, c3 = dinv[s3] * dn;
    float2 v0 = __half22float2(h2h2[(size_t)s0 * 16 + c2]);
    float2 v1 = __half22float2(h2h2[(size_t)s1 * 16 + c2]);
    float2 v2 = __half22float2(h2h2[(size_t)s2 * 16 + c2]);
    float2 v3 = __half22float2(h2h2[(size_t)s3 * 16 + c2]);
    a0 += v0.x * c0 + v1.x * c1 + v2.x * c2f + v3.x * c3;
    a1 += v0.y * c0 + v1.y * c1 + v2.y * c2f + v3.y * c3;
  }
  for (; j < cnt; j++) {
    int s = csr_src[start + j];
    float c = dinv[s] * dn;
    float2 v = __half22float2(h2h2[(size_t)s * 16 + c2]);
    a0 += v.x * c; a1 += v.y * c;
  }
  zh2[(size_t)node * 16 + c2] = __floats2half2_rn(a0 + b2[2 * c2], a1 + b2[2 * c2 + 1]);
}

// ---------------- decode: out[p] = dot(z[a], z[b])  (16 lanes/pair, half2) ----------------
__global__ __launch_bounds__(256) void k_decode(const __half2* __restrict__ zh2, const int* __restrict__ eli,
                                                float* __restrict__ out, int L) {
  int p = blockIdx.x * 16 + (threadIdx.x >> 4);
  int c2 = threadIdx.x & 15;
  if (p >= L) return;
  int a = eli[p], b = eli[L + p];
  float2 va = __half22float2(zh2[(size_t)a * 16 + c2]);
  float2 vb = __half22float2(zh2[(size_t)b * 16 + c2]);
  float v = va.x * vb.x + va.y * vb.y;
  #pragma unroll
  for (int off = 8; off >= 1; off >>= 1) v += __shfl_xor(v, off, 64);  // stays within 16-lane group
  if (c2 == 0) out[p] = v;
}

extern "C" void kernel_launch(void* const* d_in, const int* in_sizes, int n_in,
                              void* d_out, int out_size, void* d_ws, size_t ws_size,
                              hipStream_t stream) {
  const float* x   = (const float*)d_in[0];
  const int*   ei  = (const int*)d_in[1];
  const int*   eli = (const int*)d_in[2];
  const float* W1  = (const float*)d_in[3];
  const float* b1  = (const float*)d_in[4];
  const float* W2  = (const float*)d_in[5];
  const float* b2  = (const float*)d_in[6];
  float* out = (float*)d_out;

  const int N = in_sizes[0] / IN_C;
  const int E = in_sizes[1] / 2;
  const int L = in_sizes[2] / 2;
  const int* e_src = ei;
  const int* e_dst = ei + E;
  const int NB = (N + 255) >> BWL;

  char* p = (char*)d_ws;
  auto carve = [&](size_t bytes) -> void* {
    void* r = (void*)p;
    p += (bytes + 255) & ~(size_t)255;
    return r;
  };
  int*   ecnt      = (int*)  carve((size_t)N * 4);
  float* dinv      = (float*)carve((size_t)N * 4);
  int*   offsets   = (int*)  carve((size_t)N * 4);
  int*   bcnt      = (int*)  carve(NBMAX * 4);
  int*   bbase     = (int*)  carve((NBMAX + 1) * 4);
  int*   bcursor   = (int*)  carve(NBMAX * 4);
  int*   csr_src   = (int*)  carve((size_t)E * 4);            // 6.4 MB
  __half2* xh      = (__half2*)carve((size_t)N * IN_C * 2);   // 12.8 MB
  __half2* aggh    = (__half2*)carve((size_t)N * IN_C * 2);   // 12.8 MB; dead after gemm1
  __half*  h1h     = (__half*) carve((size_t)N * H1 * 2);     // 25.6 MB
  // aliases: binned (12.8 MB) in h1h space (dead before gemm1 writes h1h);
  // h2 and z in aggh space (dead after gemm1 reads it)
  unsigned long long* binned = (unsigned long long*)h1h;
  __half*  h2h = (__half*)aggh;
  __half2* h2h2 = (__half2*)aggh;
  __half2* zh2 = (__half2*)((char*)aggh + (size_t)N * H2 * 2);

  const int B = 256;
  k_init<<<1, B, 0, stream>>>(bcnt, bcursor, NB);
  k_cast<<<(N * IN_C / 4 + B - 1) / B, B, 0, stream>>>((const float4*)x, xh, N * IN_C / 4);
  k_bin<<<(E + 2047) / 2048, B, 0, stream>>>(e_dst, bcnt, E, NB);
  k_scan_bkt<<<1, B, 0, stream>>>(bcnt, bbase, NB);
  k_scatter<<<(E + 4095) / 4096, B, 0, stream>>>(e_src, e_dst, bbase, bcursor, binned, E, NB);
  k_fill2<<<NB, B, 0, stream>>>(binned, bbase, csr_src, offsets, ecnt, dinv, N, NB);
  k_agg1<<<(N + 3) / 4, B, 0, stream>>>(xh, dinv, ecnt, offsets, csr_src, aggh, N);
  k_gemm1<<<(N + NPB1 - 1) / NPB1, B, 0, stream>>>(aggh, W1, b1, h1h, N);
  k_gemm2<<<(N + NPB2 - 1) / NPB2, B, 0, stream>>>((const __half2*)h1h, W2, h2h, N);
  k_agg2<<<(N + 15) / 16, B, 0, stream>>>(h2h2, dinv, ecnt, offsets, csr_src, b2, zh2, N);
  k_decode<<<(L + 15) / 16, B, 0, stream>>>(zh2, eli, out, L);
}

// Round 6
// 311.503 us; speedup vs baseline: 1.7787x; 1.1902x over previous
//
#include <hip/hip_runtime.h>
#include <hip/hip_fp16.h>

#define IN_C 128
#define H1   256
#define H2   32
#define BWL  8              // bucket width = 256 nodes
#define NBMAX 256           // max buckets (N <= 65536)

typedef _Float16 half8 __attribute__((ext_vector_type(8)));
typedef float f32x4 __attribute__((ext_vector_type(4)));

// ---------------- init: zero bucket counters ----------------
__global__ __launch_bounds__(256) void k_init(int* bucket_cnt, int* bucket_cursor, int nb) {
  int i = blockIdx.x * blockDim.x + threadIdx.x;
  if (i < nb) { bucket_cnt[i] = 0; bucket_cursor[i] = 0; }
}

// ---------------- cast x (f32) -> xh (fp16), vectorized ----------------
__global__ __launch_bounds__(256) void k_cast(const float4* __restrict__ x4, __half2* __restrict__ xh, int n4) {
  int i = blockIdx.x * 256 + threadIdx.x;
  if (i < n4) {
    float4 v = x4[i];
    xh[2 * i]     = __floats2half2_rn(v.x, v.y);
    xh[2 * i + 1] = __floats2half2_rn(v.z, v.w);
  }
}

// ---------------- cast+transpose weights: W1 [128][256] -> W1T fp16 [256][128]; W2 [256][32] -> W2T [32][256] ----------------
__global__ __launch_bounds__(256) void k_castw(const float* __restrict__ W1, const float* __restrict__ W2,
                                               _Float16* __restrict__ W1T, _Float16* __restrict__ W2T) {
  int i = blockIdx.x * 256 + threadIdx.x;
  if (i < 128 * 256) {
    int k = i >> 8, nn = i & 255;
    W1T[nn * 128 + k] = (_Float16)W1[i];
  }
  if (i < 256 * 32) {
    int k = i >> 5, nn = i & 31;
    W2T[nn * 256 + k] = (_Float16)W2[i];
  }
}

// ---------------- bucket histogram only (NO global per-node atomics) ----------------
__global__ __launch_bounds__(256) void k_bin(const int* __restrict__ dst, int* bucket_cnt, int e, int nb) {
  __shared__ int hist[NBMAX];
  for (int u = threadIdx.x; u < nb; u += 256) hist[u] = 0;
  __syncthreads();
  int base = blockIdx.x * 2048;
  #pragma unroll
  for (int j = 0; j < 8; j++) {
    int i = base + j * 256 + threadIdx.x;
    if (i < e) atomicAdd(&hist[dst[i] >> BWL], 1);
  }
  __syncthreads();
  for (int u = threadIdx.x; u < nb; u += 256) if (hist[u]) atomicAdd(&bucket_cnt[u], hist[u]);
}

// ---------------- scan bucket counts -> bucket_base (1 block) ----------------
__global__ __launch_bounds__(256) void k_scan_bkt(const int* __restrict__ bucket_cnt,
                                                  int* __restrict__ bucket_base, int nb) {
  __shared__ int tmp[256];
  int t = threadIdx.x;
  int b = (t < nb) ? bucket_cnt[t] : 0;
  tmp[t] = b; __syncthreads();
  for (int off = 1; off < 256; off <<= 1) {
    int x = (t >= off) ? tmp[t - off] : 0;
    __syncthreads();
    tmp[t] += x;
    __syncthreads();
  }
  if (t < nb) bucket_base[t] = tmp[t] - b;
  if (t == 255) bucket_base[nb] = tmp[255];
}

// ---------------- binned partition: (src,dst) packed 8B ----------------
__global__ __launch_bounds__(256) void k_scatter(const int* __restrict__ src, const int* __restrict__ dst,
                                                 const int* __restrict__ bucket_base, int* bucket_cursor,
                                                 unsigned long long* __restrict__ binned, int e, int nb) {
  __shared__ int hist[NBMAX];
  __shared__ int wbase[NBMAX];
  int t = threadIdx.x;
  for (int u = t; u < nb; u += 256) hist[u] = 0;
  __syncthreads();
  int base = blockIdx.x * 4096;
  int s_[16], d_[16];
  #pragma unroll
  for (int j = 0; j < 16; j++) {
    int i = base + j * 256 + t;
    if (i < e) {
      s_[j] = src[i]; d_[j] = dst[i];
      atomicAdd(&hist[d_[j] >> BWL], 1);
    } else d_[j] = -1;
  }
  __syncthreads();
  for (int u = t; u < nb; u += 256) {
    int c = hist[u];
    wbase[u] = (c > 0) ? (bucket_base[u] + atomicAdd(&bucket_cursor[u], c)) : 0;
  }
  __syncthreads();
  for (int u = t; u < nb; u += 256) hist[u] = 0;
  __syncthreads();
  #pragma unroll
  for (int j = 0; j < 16; j++) {
    if (d_[j] >= 0) {
      int b = d_[j] >> BWL;
      int r = atomicAdd(&hist[b], 1);
      binned[wbase[b] + r] = ((unsigned long long)(unsigned)d_[j] << 32) | (unsigned)s_[j];
    }
  }
}

// ---------------- CSR fill: one block/bucket. LDS degree count + prefix -> offsets/ecnt/dinv, place edges ----------------
__global__ __launch_bounds__(256) void k_fill2(const unsigned long long* __restrict__ binned,
                                               const int* __restrict__ bucket_base,
                                               int* __restrict__ csr_src,
                                               int* __restrict__ offsets, int* __restrict__ ecnt,
                                               float* __restrict__ dinv, int n, int nb) {
  __shared__ int cnt[256], pre[256], cur[256], loc[256];
  int b = blockIdx.x;
  int t = threadIdx.x;
  cnt[t] = 0; cur[t] = 0;
  __syncthreads();
  int start = bucket_base[b], end = bucket_base[b + 1];
  int node0 = b << BWL;
  for (int i = start + t; i < end; i += 256) {
    int d = (int)(binned[i] >> 32);
    atomicAdd(&cnt[d - node0], 1);
  }
  __syncthreads();
  int v = cnt[t];
  pre[t] = v; __syncthreads();
  for (int off = 1; off < 256; off <<= 1) {
    int x = (t >= off) ? pre[t - off] : 0;
    __syncthreads();
    pre[t] += x;
    __syncthreads();
  }
  int excl = pre[t] - v;
  loc[t] = excl;
  int node = node0 + t;
  if (node < n) {
    offsets[node] = start + excl;
    ecnt[node] = v;
    dinv[node] = rsqrtf((float)(v + 1));
  }
  __syncthreads();
  for (int i = start + t; i < end; i += 256) {
    unsigned long long sd = binned[i];
    int s = (int)(sd & 0xffffffffULL), d = (int)(sd >> 32);
    int li = d - node0;
    int p = atomicAdd(&cur[li], 1);
    csr_src[start + loc[li] + p] = s;
  }
}

// ---------------- layer-1 aggregation: one wave/node, half2 lanes ----------------
__global__ __launch_bounds__(256) void k_agg1(const __half2* __restrict__ xh, const float* __restrict__ dinv,
                                              const int* __restrict__ ecnt, const int* __restrict__ offsets,
                                              const int* __restrict__ csr_src,
                                              __half2* __restrict__ aggh, int n) {
  int node = blockIdx.x * 4 + (threadIdx.x >> 6);
  int lane = threadIdx.x & 63;
  if (node >= n) return;
  float dn = dinv[node];
  float2 self = __half22float2(xh[(size_t)node * 64 + lane]);
  float a0 = self.x * dn * dn, a1 = self.y * dn * dn;
  int start = offsets[node];
  int cnt = ecnt[node];
  int j = 0;
  for (; j + 4 <= cnt; j += 4) {
    int   s0 = csr_src[start + j    ], s1 = csr_src[start + j + 1];
    int   s2 = csr_src[start + j + 2], s3 = csr_src[start + j + 3];
    float c0 = dinv[s0] * dn, c1 = dinv[s1] * dn;
    float c2 = dinv[s2] * dn, c3 = dinv[s3] * dn;
    float2 v0 = __half22float2(xh[(size_t)s0 * 64 + lane]);
    float2 v1 = __half22float2(xh[(size_t)s1 * 64 + lane]);
    float2 v2 = __half22float2(xh[(size_t)s2 * 64 + lane]);
    float2 v3 = __half22float2(xh[(size_t)s3 * 64 + lane]);
    a0 += v0.x * c0 + v1.x * c1 + v2.x * c2 + v3.x * c3;
    a1 += v0.y * c0 + v1.y * c1 + v2.y * c2 + v3.y * c3;
  }
  for (; j < cnt; j++) {
    int s = csr_src[start + j];
    float c = dinv[s] * dn;
    float2 v = __half22float2(xh[(size_t)s * 64 + lane]);
    a0 += v.x * c; a1 += v.y * c;
  }
  aggh[(size_t)node * 64 + lane] = __floats2half2_rn(a0, a1);
}

// ---------------- GEMM1 (MFMA): h1 = relu(agg1 @ W1 + b1). wave = 16-node M-tile, 16 N-tiles, K=128 ----------------
__global__ __launch_bounds__(256) void k_gemm1(const _Float16* __restrict__ aggh,
                                               const _Float16* __restrict__ W1T, const float* __restrict__ b1,
                                               _Float16* __restrict__ h1h, int n) {
  int wid = threadIdx.x >> 6, lane = threadIdx.x & 63;
  int quad = lane >> 4, mrow = lane & 15;
  int mbase = blockIdx.x * 64 + wid * 16;
  int node = mbase + mrow; if (node >= n) node = n - 1;   // clamp: garbage rows never stored
  const half8* A = (const half8*)aggh;                    // [node][k] ; 16 half8 per row
  const half8* B = (const half8*)W1T;                     // [n][k]    ; 16 half8 per row
  f32x4 acc[16];
  #pragma unroll
  for (int t = 0; t < 16; t++) acc[t] = (f32x4){0.f, 0.f, 0.f, 0.f};
  #pragma unroll
  for (int ks = 0; ks < 4; ks++) {                        // K = 4 x 32
    half8 a = A[(size_t)node * 16 + ks * 4 + quad];       // A[m=lane&15][k=quad*8+j]
    #pragma unroll
    for (int nt = 0; nt < 16; nt++) {
      half8 b = B[(size_t)(nt * 16 + mrow) * 16 + ks * 4 + quad];  // B[n=lane&15][k=quad*8+j]
      acc[nt] = __builtin_amdgcn_mfma_f32_16x16x32_f16(a, b, acc[nt], 0, 0, 0);
    }
  }
  #pragma unroll
  for (int nt = 0; nt < 16; nt++) {
    int c = nt * 16 + mrow;                               // C/D: col = lane&15
    float bias = b1[c];
    #pragma unroll
    for (int r = 0; r < 4; r++) {
      int m = mbase + quad * 4 + r;                       // C/D: row = quad*4 + reg
      if (m < n) h1h[(size_t)m * H1 + c] = (_Float16)fmaxf(acc[nt][r] + bias, 0.f);
    }
  }
}

// ---------------- GEMM2 (MFMA): h2 = h1 @ W2. wave = 16-node M-tile, 2 N-tiles, K=256 ----------------
__global__ __launch_bounds__(256) void k_gemm2(const _Float16* __restrict__ h1h,
                                               const _Float16* __restrict__ W2T,
                                               _Float16* __restrict__ h2h, int n) {
  int wid = threadIdx.x >> 6, lane = threadIdx.x & 63;
  int quad = lane >> 4, mrow = lane & 15;
  int mbase = blockIdx.x * 64 + wid * 16;
  int node = mbase + mrow; if (node >= n) node = n - 1;
  const half8* A = (const half8*)h1h;                     // [node][k] ; 32 half8 per row
  const half8* B = (const half8*)W2T;                     // [n][k]    ; 32 half8 per row (16 KB, L1-resident)
  f32x4 acc[2];
  acc[0] = (f32x4){0.f, 0.f, 0.f, 0.f};
  acc[1] = (f32x4){0.f, 0.f, 0.f, 0.f};
  #pragma unroll
  for (int ks = 0; ks < 8; ks++) {                        // K = 8 x 32
    half8 a = A[(size_t)node * 32 + ks * 4 + quad];
    #pragma unroll
    for (int nt = 0; nt < 2; nt++) {
      half8 b = B[(size_t)(nt * 16 + mrow) * 32 + ks * 4 + quad];
      acc[nt] = __builtin_amdgcn_mfma_f32_16x16x32_f16(a, b, acc[nt], 0, 0, 0);
    }
  }
  #pragma unroll
  for (int nt = 0; nt < 2; nt++) {
    int c = nt * 16 + mrow;
    #pragma unroll
    for (int r = 0; r < 4; r++) {
      int m = mbase + quad * 4 + r;
      if (m < n) h2h[(size_t)m * H2 + c] = (_Float16)acc[nt][r];   // bias after aggregation
    }
  }
}

// ---------------- layer-2 aggregation: z = A @ h2 + b2  (16 lanes/node, half2) ----------------
__global__ __launch_bounds__(256) void k_agg2(const __half2* __restrict__ h2h2, const float* __restrict__ dinv,
                                              const int* __restrict__ ecnt, const int* __restrict__ offsets,
                                              const int* __restrict__ csr_src,
                                              const float* __restrict__ b2, __half2* __restrict__ zh2, int n) {
  int node = blockIdx.x * 16 + (threadIdx.x >> 4);
  int c2 = threadIdx.x & 15;
  if (node >= n) return;
  float dn = dinv[node];
  float2 self = __half22float2(h2h2[(size_t)node * 16 + c2]);
  float a0 = self.x * dn * dn, a1 = self.y * dn * dn;
  int start = offsets[node];
  int cnt = ecnt[node];
  int j = 0;
  for (; j + 4 <= cnt; j += 4) {
    int   s0 = csr_src[start + j    ], s1 = csr_src[start + j + 1];
    int   s2 = csr_src[start + j + 2], s3 = csr_src[start + j + 3];
    float c0 = dinv[s0] * dn, c1 = dinv[s1] * dn;
    float c2f = dinv[s2] * dn, c3 = dinv[s3] * dn;
    float2 v0 = __half22float2(h2h2[(size_t)s0 * 16 + c2]);
    float2 v1 = __half22float2(h2h2[(size_t)s1 * 16 + c2]);
    float2 v2 = __half22float2(h2h2[(size_t)s2 * 16 + c2]);
    float2 v3 = __half22float2(h2h2[(size_t)s3 * 16 + c2]);
    a0 += v0.x * c0 + v1.x * c1 + v2.x * c2f + v3.x * c3;
    a1 += v0.y * c0 + v1.y * c1 + v2.y * c2f + v3.y * c3;
  }
  for (; j < cnt; j++) {
    int s = csr_src[start + j];
    float c = dinv[s] * dn;
    float2 v = __half22float2(h2h2[(size_t)s * 16 + c2]);
    a0 += v.x * c; a1 += v.y * c;
  }
  zh2[(size_t)node * 16 + c2] = __floats2half2_rn(a0 + b2[2 * c2], a1 + b2[2 * c2 + 1]);
}

// ---------------- decode: out[p] = dot(z[a], z[b])  (16 lanes/pair, half2) ----------------
__global__ __launch_bounds__(256) void k_decode(const __half2* __restrict__ zh2, const int* __restrict__ eli,
                                                float* __restrict__ out, int L) {
  int p = blockIdx.x * 16 + (threadIdx.x >> 4);
  int c2 = threadIdx.x & 15;
  if (p >= L) return;
  int a = eli[p], b = eli[L + p];
  float2 va = __half22float2(zh2[(size_t)a * 16 + c2]);
  float2 vb = __half22float2(zh2[(size_t)b * 16 + c2]);
  float v = va.x * vb.x + va.y * vb.y;
  #pragma unroll
  for (int off = 8; off >= 1; off >>= 1) v += __shfl_xor(v, off, 64);
  if (c2 == 0) out[p] = v;
}

extern "C" void kernel_launch(void* const* d_in, const int* in_sizes, int n_in,
                              void* d_out, int out_size, void* d_ws, size_t ws_size,
                              hipStream_t stream) {
  const float* x   = (const float*)d_in[0];
  const int*   ei  = (const int*)d_in[1];
  const int*   eli = (const int*)d_in[2];
  const float* W1  = (const float*)d_in[3];
  const float* b1  = (const float*)d_in[4];
  const float* W2  = (const float*)d_in[5];
  const float* b2  = (const float*)d_in[6];
  float* out = (float*)d_out;

  const int N = in_sizes[0] / IN_C;
  const int E = in_sizes[1] / 2;
  const int L = in_sizes[2] / 2;
  const int* e_src = ei;
  const int* e_dst = ei + E;
  const int NB = (N + 255) >> BWL;

  char* p = (char*)d_ws;
  auto carve = [&](size_t bytes) -> void* {
    void* r = (void*)p;
    p += (bytes + 255) & ~(size_t)255;
    return r;
  };
  int*   ecnt      = (int*)  carve((size_t)N * 4);
  float* dinv      = (float*)carve((size_t)N * 4);
  int*   offsets   = (int*)  carve((size_t)N * 4);
  int*   bcnt      = (int*)  carve(NBMAX * 4);
  int*   bbase     = (int*)  carve((NBMAX + 1) * 4);
  int*   bcursor   = (int*)  carve(NBMAX * 4);
  _Float16* W1T    = (_Float16*)carve(256 * 128 * 2);         // 64 KB
  _Float16* W2T    = (_Float16*)carve(32 * 256 * 2);          // 16 KB
  int*   csr_src   = (int*)  carve((size_t)E * 4);            // 6.4 MB
  __half2* xh      = (__half2*)carve((size_t)N * IN_C * 2);   // 12.8 MB
  __half2* aggh    = (__half2*)carve(((size_t)N + 64) * IN_C * 2); // 12.8 MB (+pad rows for clamped loads)
  __half*  h1h     = (__half*) carve(((size_t)N + 64) * H1 * 2);   // 25.6 MB
  unsigned long long* binned = (unsigned long long*)h1h;      // alias: dead before gemm1 writes h1h
  __half*  h2h = (__half*)aggh;                               // alias: aggh dead after gemm1 reads it
  __half2* h2h2 = (__half2*)aggh;
  __half2* zh2 = (__half2*)((char*)aggh + (size_t)N * H2 * 2);

  const int B = 256;
  k_init<<<1, B, 0, stream>>>(bcnt, bcursor, NB);
  k_cast<<<(N * IN_C / 4 + B - 1) / B, B, 0, stream>>>((const float4*)x, xh, N * IN_C / 4);
  k_castw<<<128, B, 0, stream>>>(W1, W2, W1T, W2T);
  k_bin<<<(E + 2047) / 2048, B, 0, stream>>>(e_dst, bcnt, E, NB);
  k_scan_bkt<<<1, B, 0, stream>>>(bcnt, bbase, NB);
  k_scatter<<<(E + 4095) / 4096, B, 0, stream>>>(e_src, e_dst, bbase, bcursor, binned, E, NB);
  k_fill2<<<NB, B, 0, stream>>>(binned, bbase, csr_src, offsets, ecnt, dinv, N, NB);
  k_agg1<<<(N + 3) / 4, B, 0, stream>>>(xh, dinv, ecnt, offsets, csr_src, aggh, N);
  k_gemm1<<<(N + 63) / 64, B, 0, stream>>>((const _Float16*)aggh, W1T, b1, (_Float16*)h1h, N);
  k_gemm2<<<(N + 63) / 64, B, 0, stream>>>((const _Float16*)h1h, W2T, (_Float16*)h2h, N);
  k_agg2<<<(N + 15) / 16, B, 0, stream>>>(h2h2, dinv, ecnt, offsets, csr_src, b2, zh2, N);
  k_decode<<<(L + 15) / 16, B, 0, stream>>>(zh2, eli, out, L);
}

// Round 7
// 300.644 us; speedup vs baseline: 1.8429x; 1.0361x over previous
//
#include <hip/hip_runtime.h>
#include <hip/hip_fp16.h>

#define IN_C 128
#define H1   256
#define H2   32
#define BWL  8              // bucket width = 256 nodes
#define NBMAX 256           // max buckets (N <= 65536)

typedef _Float16 half8 __attribute__((ext_vector_type(8)));
typedef _Float16 h2    __attribute__((ext_vector_type(2)));
typedef float f32x4 __attribute__((ext_vector_type(4)));

// ---------------- init: zero bucket counters ----------------
__global__ __launch_bounds__(256) void k_init(int* bucket_cnt, int* bucket_cursor, int nb) {
  int i = blockIdx.x * blockDim.x + threadIdx.x;
  if (i < nb) { bucket_cnt[i] = 0; bucket_cursor[i] = 0; }
}

// ---------------- cast+scale x: xh[node] = (fp16)(x[node] * dinv[node])  (runs AFTER fill2) ----------------
__global__ __launch_bounds__(256) void k_cast(const float4* __restrict__ x4, const float* __restrict__ dinv,
                                              h2* __restrict__ xh, int n4) {
  int i = blockIdx.x * 256 + threadIdx.x;
  if (i < n4) {
    float4 v = x4[i];
    float dn = dinv[i >> 5];                 // 32 float4 per node (IN_C=128)
    h2 a, b;
    a[0] = (_Float16)(v.x * dn); a[1] = (_Float16)(v.y * dn);
    b[0] = (_Float16)(v.z * dn); b[1] = (_Float16)(v.w * dn);
    xh[2 * i] = a; xh[2 * i + 1] = b;
  }
}

// ---------------- cast+transpose weights: W1 [128][256] -> W1T fp16 [256][128]; W2 [256][32] -> W2T [32][256] ----------------
__global__ __launch_bounds__(256) void k_castw(const float* __restrict__ W1, const float* __restrict__ W2,
                                               _Float16* __restrict__ W1T, _Float16* __restrict__ W2T) {
  int i = blockIdx.x * 256 + threadIdx.x;
  if (i < 128 * 256) {
    int k = i >> 8, nn = i & 255;
    W1T[nn * 128 + k] = (_Float16)W1[i];
  }
  if (i < 256 * 32) {
    int k = i >> 5, nn = i & 31;
    W2T[nn * 256 + k] = (_Float16)W2[i];
  }
}

// ---------------- bucket histogram only (NO global per-node atomics) ----------------
__global__ __launch_bounds__(256) void k_bin(const int* __restrict__ dst, int* bucket_cnt, int e, int nb) {
  __shared__ int hist[NBMAX];
  for (int u = threadIdx.x; u < nb; u += 256) hist[u] = 0;
  __syncthreads();
  int base = blockIdx.x * 2048;
  #pragma unroll
  for (int j = 0; j < 8; j++) {
    int i = base + j * 256 + threadIdx.x;
    if (i < e) atomicAdd(&hist[dst[i] >> BWL], 1);
  }
  __syncthreads();
  for (int u = threadIdx.x; u < nb; u += 256) if (hist[u]) atomicAdd(&bucket_cnt[u], hist[u]);
}

// ---------------- scan bucket counts -> bucket_base (1 block) ----------------
__global__ __launch_bounds__(256) void k_scan_bkt(const int* __restrict__ bucket_cnt,
                                                  int* __restrict__ bucket_base, int nb) {
  __shared__ int tmp[256];
  int t = threadIdx.x;
  int b = (t < nb) ? bucket_cnt[t] : 0;
  tmp[t] = b; __syncthreads();
  for (int off = 1; off < 256; off <<= 1) {
    int x = (t >= off) ? tmp[t - off] : 0;
    __syncthreads();
    tmp[t] += x;
    __syncthreads();
  }
  if (t < nb) bucket_base[t] = tmp[t] - b;
  if (t == 255) bucket_base[nb] = tmp[255];
}

// ---------------- binned partition: (src,dst) packed 8B ----------------
__global__ __launch_bounds__(256) void k_scatter(const int* __restrict__ src, const int* __restrict__ dst,
                                                 const int* __restrict__ bucket_base, int* bucket_cursor,
                                                 unsigned long long* __restrict__ binned, int e, int nb) {
  __shared__ int hist[NBMAX];
  __shared__ int wbase[NBMAX];
  int t = threadIdx.x;
  for (int u = t; u < nb; u += 256) hist[u] = 0;
  __syncthreads();
  int base = blockIdx.x * 4096;
  int s_[16], d_[16];
  #pragma unroll
  for (int j = 0; j < 16; j++) {
    int i = base + j * 256 + t;
    if (i < e) {
      s_[j] = src[i]; d_[j] = dst[i];
      atomicAdd(&hist[d_[j] >> BWL], 1);
    } else d_[j] = -1;
  }
  __syncthreads();
  for (int u = t; u < nb; u += 256) {
    int c = hist[u];
    wbase[u] = (c > 0) ? (bucket_base[u] + atomicAdd(&bucket_cursor[u], c)) : 0;
  }
  __syncthreads();
  for (int u = t; u < nb; u += 256) hist[u] = 0;
  __syncthreads();
  #pragma unroll
  for (int j = 0; j < 16; j++) {
    if (d_[j] >= 0) {
      int b = d_[j] >> BWL;
      int r = atomicAdd(&hist[b], 1);
      binned[wbase[b] + r] = ((unsigned long long)(unsigned)d_[j] << 32) | (unsigned)s_[j];
    }
  }
}

// ---------------- CSR fill: one block/bucket. LDS degree count + prefix -> offsets/ecnt/dinv, place edges ----------------
__global__ __launch_bounds__(256) void k_fill2(const unsigned long long* __restrict__ binned,
                                               const int* __restrict__ bucket_base,
                                               int* __restrict__ csr_src,
                                               int* __restrict__ offsets, int* __restrict__ ecnt,
                                               float* __restrict__ dinv, int n, int nb) {
  __shared__ int cnt[256], pre[256], cur[256], loc[256];
  int b = blockIdx.x;
  int t = threadIdx.x;
  cnt[t] = 0; cur[t] = 0;
  __syncthreads();
  int start = bucket_base[b], end = bucket_base[b + 1];
  int node0 = b << BWL;
  for (int i = start + t; i < end; i += 256) {
    int d = (int)(binned[i] >> 32);
    atomicAdd(&cnt[d - node0], 1);
  }
  __syncthreads();
  int v = cnt[t];
  pre[t] = v; __syncthreads();
  for (int off = 1; off < 256; off <<= 1) {
    int x = (t >= off) ? pre[t - off] : 0;
    __syncthreads();
    pre[t] += x;
    __syncthreads();
  }
  int excl = pre[t] - v;
  loc[t] = excl;
  int node = node0 + t;
  if (node < n) {
    offsets[node] = start + excl;
    ecnt[node] = v;
    dinv[node] = rsqrtf((float)(v + 1));
  }
  __syncthreads();
  for (int i = start + t; i < end; i += 256) {
    unsigned long long sd = binned[i];
    int s = (int)(sd & 0xffffffffULL), d = (int)(sd >> 32);
    int li = d - node0;
    int p = atomicAdd(&cur[li], 1);
    csr_src[start + loc[li] + p] = s;
  }
}

// ---------------- layer-1 aggregation: agg1 = dn*(sum x~[s] + x~[node]); pk_add_f16 chunks, f32 flush ----------------
__global__ __launch_bounds__(256) void k_agg1(const h2* __restrict__ xh, const float* __restrict__ dinv,
                                              const int* __restrict__ ecnt, const int* __restrict__ offsets,
                                              const int* __restrict__ csr_src,
                                              h2* __restrict__ aggh, int n) {
  int node = blockIdx.x * 4 + (threadIdx.x >> 6);
  int lane = threadIdx.x & 63;                 // half2 index 0..63 (128 ch)
  if (node >= n) return;
  float dn = dinv[node];
  h2 selfv = xh[(size_t)node * 64 + lane];     // x~[node] = x[node]*dn  (self coef dn^2 = dn * x~)
  float a0 = (float)selfv[0], a1 = (float)selfv[1];
  int start = offsets[node];
  int cnt = ecnt[node];
  int j = 0;
  for (; j + 8 <= cnt; j += 8) {
    int s0 = csr_src[start + j    ], s1 = csr_src[start + j + 1];
    int s2 = csr_src[start + j + 2], s3 = csr_src[start + j + 3];
    int s4 = csr_src[start + j + 4], s5 = csr_src[start + j + 5];
    int s6 = csr_src[start + j + 6], s7 = csr_src[start + j + 7];
    h2 v0 = xh[(size_t)s0 * 64 + lane], v1 = xh[(size_t)s1 * 64 + lane];
    h2 v2 = xh[(size_t)s2 * 64 + lane], v3 = xh[(size_t)s3 * 64 + lane];
    h2 v4 = xh[(size_t)s4 * 64 + lane], v5 = xh[(size_t)s5 * 64 + lane];
    h2 v6 = xh[(size_t)s6 * 64 + lane], v7 = xh[(size_t)s7 * 64 + lane];
    h2 p = ((v0 + v1) + (v2 + v3)) + ((v4 + v5) + (v6 + v7));   // tree of v_pk_add_f16
    a0 += (float)p[0]; a1 += (float)p[1];                       // f32 flush per chunk
  }
  h2 tail = {(_Float16)0.f, (_Float16)0.f};
  for (; j < cnt; j++) tail += xh[(size_t)csr_src[start + j] * 64 + lane];
  a0 += (float)tail[0]; a1 += (float)tail[1];
  a0 *= dn; a1 *= dn;
  h2 o; o[0] = (_Float16)a0; o[1] = (_Float16)a1;
  aggh[(size_t)node * 64 + lane] = o;
}

// ---------------- GEMM1 (MFMA): h1 = relu(agg1 @ W1 + b1). wave = 16-node M-tile, 16 N-tiles, K=128 ----------------
__global__ __launch_bounds__(256) void k_gemm1(const _Float16* __restrict__ aggh,
                                               const _Float16* __restrict__ W1T, const float* __restrict__ b1,
                                               _Float16* __restrict__ h1h, int n) {
  int wid = threadIdx.x >> 6, lane = threadIdx.x & 63;
  int quad = lane >> 4, mrow = lane & 15;
  int mbase = blockIdx.x * 64 + wid * 16;
  int node = mbase + mrow; if (node >= n) node = n - 1;   // clamp: garbage rows never stored
  const half8* A = (const half8*)aggh;                    // [node][k] ; 16 half8 per row
  const half8* B = (const half8*)W1T;                     // [n][k]    ; 16 half8 per row
  f32x4 acc[16];
  #pragma unroll
  for (int t = 0; t < 16; t++) acc[t] = (f32x4){0.f, 0.f, 0.f, 0.f};
  #pragma unroll
  for (int ks = 0; ks < 4; ks++) {                        // K = 4 x 32
    half8 a = A[(size_t)node * 16 + ks * 4 + quad];       // A[m=lane&15][k=quad*8+j]
    #pragma unroll
    for (int nt = 0; nt < 16; nt++) {
      half8 b = B[(size_t)(nt * 16 + mrow) * 16 + ks * 4 + quad];  // B[n=lane&15][k=quad*8+j]
      acc[nt] = __builtin_amdgcn_mfma_f32_16x16x32_f16(a, b, acc[nt], 0, 0, 0);
    }
  }
  #pragma unroll
  for (int nt = 0; nt < 16; nt++) {
    int c = nt * 16 + mrow;                               // C/D: col = lane&15
    float bias = b1[c];
    #pragma unroll
    for (int r = 0; r < 4; r++) {
      int m = mbase + quad * 4 + r;                       // C/D: row = quad*4 + reg
      if (m < n) h1h[(size_t)m * H1 + c] = (_Float16)fmaxf(acc[nt][r] + bias, 0.f);
    }
  }
}

// ---------------- GEMM2 (MFMA): h2~ = (h1 @ W2) * dinv[m]. wave = 16-node M-tile, 2 N-tiles, K=256 ----------------
__global__ __launch_bounds__(256) void k_gemm2(const _Float16* __restrict__ h1h,
                                               const _Float16* __restrict__ W2T, const float* __restrict__ dinv,
                                               _Float16* __restrict__ h2h, int n) {
  int wid = threadIdx.x >> 6, lane = threadIdx.x & 63;
  int quad = lane >> 4, mrow = lane & 15;
  int mbase = blockIdx.x * 64 + wid * 16;
  int node = mbase + mrow; if (node >= n) node = n - 1;
  const half8* A = (const half8*)h1h;                     // [node][k] ; 32 half8 per row
  const half8* B = (const half8*)W2T;                     // [n][k]    ; 32 half8 per row (16 KB, L1-resident)
  f32x4 acc[2];
  acc[0] = (f32x4){0.f, 0.f, 0.f, 0.f};
  acc[1] = (f32x4){0.f, 0.f, 0.f, 0.f};
  #pragma unroll
  for (int ks = 0; ks < 8; ks++) {                        // K = 8 x 32
    half8 a = A[(size_t)node * 32 + ks * 4 + quad];
    #pragma unroll
    for (int nt = 0; nt < 2; nt++) {
      half8 b = B[(size_t)(nt * 16 + mrow) * 32 + ks * 4 + quad];
      acc[nt] = __builtin_amdgcn_mfma_f32_16x16x32_f16(a, b, acc[nt], 0, 0, 0);
    }
  }
  #pragma unroll
  for (int nt = 0; nt < 2; nt++) {
    int c = nt * 16 + mrow;
    #pragma unroll
    for (int r = 0; r < 4; r++) {
      int m = mbase + quad * 4 + r;
      if (m < n) h2h[(size_t)m * H2 + c] = (_Float16)(acc[nt][r] * dinv[m]);  // pre-scaled for agg2
    }
  }
}

// ---------------- layer-2 aggregation: z = dn*(sum h2~[s] + h2~[node]) + b2  (16 lanes/node) ----------------
__global__ __launch_bounds__(256) void k_agg2(const h2* __restrict__ h2h2, const float* __restrict__ dinv,
                                              const int* __restrict__ ecnt, const int* __restrict__ offsets,
                                              const int* __restrict__ csr_src,
                                              const float* __restrict__ b2, h2* __restrict__ zh2, int n) {
  int node = blockIdx.x * 16 + (threadIdx.x >> 4);
  int c2 = threadIdx.x & 15;                   // half2 index 0..15 (32 ch)
  if (node >= n) return;
  float dn = dinv[node];
  h2 selfv = h2h2[(size_t)node * 16 + c2];
  float a0 = (float)selfv[0], a1 = (float)selfv[1];
  int start = offsets[node];
  int cnt = ecnt[node];
  int j = 0;
  for (; j + 8 <= cnt; j += 8) {
    int s0 = csr_src[start + j    ], s1 = csr_src[start + j + 1];
    int s2 = csr_src[start + j + 2], s3 = csr_src[start + j + 3];
    int s4 = csr_src[start + j + 4], s5 = csr_src[start + j + 5];
    int s6 = csr_src[start + j + 6], s7 = csr_src[start + j + 7];
    h2 v0 = h2h2[(size_t)s0 * 16 + c2], v1 = h2h2[(size_t)s1 * 16 + c2];
    h2 v2 = h2h2[(size_t)s2 * 16 + c2], v3 = h2h2[(size_t)s3 * 16 + c2];
    h2 v4 = h2h2[(size_t)s4 * 16 + c2], v5 = h2h2[(size_t)s5 * 16 + c2];
    h2 v6 = h2h2[(size_t)s6 * 16 + c2], v7 = h2h2[(size_t)s7 * 16 + c2];
    h2 p = ((v0 + v1) + (v2 + v3)) + ((v4 + v5) + (v6 + v7));
    a0 += (float)p[0]; a1 += (float)p[1];
  }
  h2 tail = {(_Float16)0.f, (_Float16)0.f};
  for (; j < cnt; j++) tail += h2h2[(size_t)csr_src[start + j] * 16 + c2];
  a0 += (float)tail[0]; a1 += (float)tail[1];
  a0 = a0 * dn + b2[2 * c2];
  a1 = a1 * dn + b2[2 * c2 + 1];
  h2 o; o[0] = (_Float16)a0; o[1] = (_Float16)a1;
  zh2[(size_t)node * 16 + c2] = o;
}

// ---------------- decode: out[p] = dot(z[a], z[b])  (16 lanes/pair, fdot2) ----------------
__global__ __launch_bounds__(256) void k_decode(const h2* __restrict__ zh2, const int* __restrict__ eli,
                                                float* __restrict__ out, int L) {
  int p = blockIdx.x * 16 + (threadIdx.x >> 4);
  int c2 = threadIdx.x & 15;
  if (p >= L) return;
  int a = eli[p], b = eli[L + p];
  h2 za = zh2[(size_t)a * 16 + c2];
  h2 zb = zh2[(size_t)b * 16 + c2];
  float v = __builtin_amdgcn_fdot2(za, zb, 0.f, false);
  #pragma unroll
  for (int off = 8; off >= 1; off >>= 1) v += __shfl_xor(v, off, 64);  // stays within 16-lane group
  if (c2 == 0) out[p] = v;
}

extern "C" void kernel_launch(void* const* d_in, const int* in_sizes, int n_in,
                              void* d_out, int out_size, void* d_ws, size_t ws_size,
                              hipStream_t stream) {
  const float* x   = (const float*)d_in[0];
  const int*   ei  = (const int*)d_in[1];
  const int*   eli = (const int*)d_in[2];
  const float* W1  = (const float*)d_in[3];
  const float* b1  = (const float*)d_in[4];
  const float* W2  = (const float*)d_in[5];
  const float* b2  = (const float*)d_in[6];
  float* out = (float*)d_out;

  const int N = in_sizes[0] / IN_C;
  const int E = in_sizes[1] / 2;
  const int L = in_sizes[2] / 2;
  const int* e_src = ei;
  const int* e_dst = ei + E;
  const int NB = (N + 255) >> BWL;

  char* p = (char*)d_ws;
  auto carve = [&](size_t bytes) -> void* {
    void* r = (void*)p;
    p += (bytes + 255) & ~(size_t)255;
    return r;
  };
  int*   ecnt      = (int*)  carve((size_t)N * 4);
  float* dinv      = (float*)carve((size_t)N * 4);
  int*   offsets   = (int*)  carve((size_t)N * 4);
  int*   bcnt      = (int*)  carve(NBMAX * 4);
  int*   bbase     = (int*)  carve((NBMAX + 1) * 4);
  int*   bcursor   = (int*)  carve(NBMAX * 4);
  _Float16* W1T    = (_Float16*)carve(256 * 128 * 2);         // 64 KB
  _Float16* W2T    = (_Float16*)carve(32 * 256 * 2);          // 16 KB
  int*   csr_src   = (int*)  carve((size_t)E * 4);            // 6.4 MB
  h2*    xh        = (h2*)   carve((size_t)N * IN_C * 2);     // 12.8 MB
  h2*    aggh      = (h2*)   carve(((size_t)N + 64) * IN_C * 2); // 12.8 MB (+pad rows for clamped loads)
  __half* h1h      = (__half*)carve(((size_t)N + 64) * H1 * 2);  // 25.6 MB
  unsigned long long* binned = (unsigned long long*)h1h;      // alias: dead before gemm1 writes h1h
  _Float16* h2h = (_Float16*)aggh;                            // alias: aggh dead after gemm1 reads it
  h2*    h2h2 = (h2*)aggh;
  h2*    zh2 = (h2*)((char*)aggh + (size_t)N * H2 * 2);

  const int B = 256;
  k_init<<<1, B, 0, stream>>>(bcnt, bcursor, NB);
  k_castw<<<128, B, 0, stream>>>(W1, W2, W1T, W2T);
  k_bin<<<(E + 2047) / 2048, B, 0, stream>>>(e_dst, bcnt, E, NB);
  k_scan_bkt<<<1, B, 0, stream>>>(bcnt, bbase, NB);
  k_scatter<<<(E + 4095) / 4096, B, 0, stream>>>(e_src, e_dst, bbase, bcursor, binned, E, NB);
  k_fill2<<<NB, B, 0, stream>>>(binned, bbase, csr_src, offsets, ecnt, dinv, N, NB);
  k_cast<<<(N * IN_C / 4 + B - 1) / B, B, 0, stream>>>((const float4*)x, dinv, xh, N * IN_C / 4);
  k_agg1<<<(N + 3) / 4, B, 0, stream>>>(xh, dinv, ecnt, offsets, csr_src, aggh, N);
  k_gemm1<<<(N + 63) / 64, B, 0, stream>>>((const _Float16*)aggh, W1T, b1, (_Float16*)h1h, N);
  k_gemm2<<<(N + 63) / 64, B, 0, stream>>>((const _Float16*)h1h, W2T, dinv, h2h, N);
  k_agg2<<<(N + 15) / 16, B, 0, stream>>>(h2h2, dinv, ecnt, offsets, csr_src, b2, zh2, N);
  k_decode<<<(L + 15) / 16, B, 0, stream>>>(zh2, eli, out, L);
}

// Round 8
// 292.131 us; speedup vs baseline: 1.8966x; 1.0291x over previous
//
#include <hip/hip_runtime.h>
#include <hip/hip_fp16.h>

#define IN_C 128
#define H1   256
#define H2   32
#define BWL  8              // bucket width = 256 nodes
#define NBMAX 256           // max buckets (N <= 65536)

typedef _Float16 half8 __attribute__((ext_vector_type(8)));
typedef _Float16 h2    __attribute__((ext_vector_type(2)));
typedef float f32x4 __attribute__((ext_vector_type(4)));

// ---------------- init: zero bucket counters ----------------
__global__ __launch_bounds__(256) void k_init(int* bucket_cnt, int* bucket_cursor, int nb) {
  int i = blockIdx.x * blockDim.x + threadIdx.x;
  if (i < nb) { bucket_cnt[i] = 0; bucket_cursor[i] = 0; }
}

// ---------------- cast+scale x: xh[node] = (fp16)(x[node] * dinv[node])  (runs AFTER fill2) ----------------
__global__ __launch_bounds__(256) void k_cast(const float4* __restrict__ x4, const float* __restrict__ dinv,
                                              h2* __restrict__ xh, int n4) {
  int i = blockIdx.x * 256 + threadIdx.x;
  if (i < n4) {
    float4 v = x4[i];
    float dn = dinv[i >> 5];                 // 32 float4 per node (IN_C=128)
    h2 a, b;
    a[0] = (_Float16)(v.x * dn); a[1] = (_Float16)(v.y * dn);
    b[0] = (_Float16)(v.z * dn); b[1] = (_Float16)(v.w * dn);
    xh[2 * i] = a; xh[2 * i + 1] = b;
  }
}

// ---------------- cast weights into MFMA-fragment-swizzled fp16 layout ----------------
// W1s half index i: d=i>>3 (half8), j=i&7; d = (nt*4+ks)*64 + quad*16 + mrow
//   value = W1[k=ks*32+quad*8+j][n=nt*16+mrow]   (W1 row-major [128][256])
// W2s: d = (nt*8+ks)*64 + quad*16 + mrow; value = W2[k=ks*32+quad*8+j][n=nt*16+mrow]  (W2 [256][32])
// => in the GEMM, B-fragment load for (nt,ks) is B8[(nt*K4+ks)*64 + lane] : lane-contiguous, coalesced.
__global__ __launch_bounds__(256) void k_castw(const float* __restrict__ W1, const float* __restrict__ W2,
                                               _Float16* __restrict__ W1s, _Float16* __restrict__ W2s) {
  int i = blockIdx.x * 256 + threadIdx.x;
  if (i < 128 * 256) {
    int d = i >> 3, j = i & 7;
    int mrow = d & 15, quad = (d >> 4) & 3, ks = (d >> 6) & 3, nt = d >> 8;
    W1s[i] = (_Float16)W1[(ks * 32 + quad * 8 + j) * 256 + nt * 16 + mrow];
  }
  if (i < 32 * 256) {
    int d = i >> 3, j = i & 7;
    int mrow = d & 15, quad = (d >> 4) & 3, ks = (d >> 6) & 7, nt = d >> 9;
    W2s[i] = (_Float16)W2[(ks * 32 + quad * 8 + j) * 32 + nt * 16 + mrow];
  }
}

// ---------------- bucket histogram only (NO global per-node atomics) ----------------
__global__ __launch_bounds__(256) void k_bin(const int* __restrict__ dst, int* bucket_cnt, int e, int nb) {
  __shared__ int hist[NBMAX];
  for (int u = threadIdx.x; u < nb; u += 256) hist[u] = 0;
  __syncthreads();
  int base = blockIdx.x * 2048;
  #pragma unroll
  for (int j = 0; j < 8; j++) {
    int i = base + j * 256 + threadIdx.x;
    if (i < e) atomicAdd(&hist[dst[i] >> BWL], 1);
  }
  __syncthreads();
  for (int u = threadIdx.x; u < nb; u += 256) if (hist[u]) atomicAdd(&bucket_cnt[u], hist[u]);
}

// ---------------- scan bucket counts -> bucket_base (1 block) ----------------
__global__ __launch_bounds__(256) void k_scan_bkt(const int* __restrict__ bucket_cnt,
                                                  int* __restrict__ bucket_base, int nb) {
  __shared__ int tmp[256];
  int t = threadIdx.x;
  int b = (t < nb) ? bucket_cnt[t] : 0;
  tmp[t] = b; __syncthreads();
  for (int off = 1; off < 256; off <<= 1) {
    int x = (t >= off) ? tmp[t - off] : 0;
    __syncthreads();
    tmp[t] += x;
    __syncthreads();
  }
  if (t < nb) bucket_base[t] = tmp[t] - b;
  if (t == 255) bucket_base[nb] = tmp[255];
}

// ---------------- binned partition: (src,dst) packed 8B ----------------
__global__ __launch_bounds__(256) void k_scatter(const int* __restrict__ src, const int* __restrict__ dst,
                                                 const int* __restrict__ bucket_base, int* bucket_cursor,
                                                 unsigned long long* __restrict__ binned, int e, int nb) {
  __shared__ int hist[NBMAX];
  __shared__ int wbase[NBMAX];
  int t = threadIdx.x;
  for (int u = t; u < nb; u += 256) hist[u] = 0;
  __syncthreads();
  int base = blockIdx.x * 4096;
  int s_[16], d_[16];
  #pragma unroll
  for (int j = 0; j < 16; j++) {
    int i = base + j * 256 + t;
    if (i < e) {
      s_[j] = src[i]; d_[j] = dst[i];
      atomicAdd(&hist[d_[j] >> BWL], 1);
    } else d_[j] = -1;
  }
  __syncthreads();
  for (int u = t; u < nb; u += 256) {
    int c = hist[u];
    wbase[u] = (c > 0) ? (bucket_base[u] + atomicAdd(&bucket_cursor[u], c)) : 0;
  }
  __syncthreads();
  for (int u = t; u < nb; u += 256) hist[u] = 0;
  __syncthreads();
  #pragma unroll
  for (int j = 0; j < 16; j++) {
    if (d_[j] >= 0) {
      int b = d_[j] >> BWL;
      int r = atomicAdd(&hist[b], 1);
      binned[wbase[b] + r] = ((unsigned long long)(unsigned)d_[j] << 32) | (unsigned)s_[j];
    }
  }
}

// ---------------- CSR fill: one block/bucket. LDS degree count + prefix -> offsets/ecnt/dinv, place edges ----------------
__global__ __launch_bounds__(256) void k_fill2(const unsigned long long* __restrict__ binned,
                                               const int* __restrict__ bucket_base,
                                               int* __restrict__ csr_src,
                                               int* __restrict__ offsets, int* __restrict__ ecnt,
                                               float* __restrict__ dinv, int n, int nb) {
  __shared__ int cnt[256], pre[256], cur[256], loc[256];
  int b = blockIdx.x;
  int t = threadIdx.x;
  cnt[t] = 0; cur[t] = 0;
  __syncthreads();
  int start = bucket_base[b], end = bucket_base[b + 1];
  int node0 = b << BWL;
  for (int i = start + t; i < end; i += 256) {
    int d = (int)(binned[i] >> 32);
    atomicAdd(&cnt[d - node0], 1);
  }
  __syncthreads();
  int v = cnt[t];
  pre[t] = v; __syncthreads();
  for (int off = 1; off < 256; off <<= 1) {
    int x = (t >= off) ? pre[t - off] : 0;
    __syncthreads();
    pre[t] += x;
    __syncthreads();
  }
  int excl = pre[t] - v;
  loc[t] = excl;
  int node = node0 + t;
  if (node < n) {
    offsets[node] = start + excl;
    ecnt[node] = v;
    dinv[node] = rsqrtf((float)(v + 1));
  }
  __syncthreads();
  for (int i = start + t; i < end; i += 256) {
    unsigned long long sd = binned[i];
    int s = (int)(sd & 0xffffffffULL), d = (int)(sd >> 32);
    int li = d - node0;
    int p = atomicAdd(&cur[li], 1);
    csr_src[start + loc[li] + p] = s;
  }
}

// ---------------- layer-1 aggregation: agg1 = dn*(sum x~[s] + x~[node]); pk_add_f16 chunks, f32 flush ----------------
__global__ __launch_bounds__(256) void k_agg1(const h2* __restrict__ xh, const float* __restrict__ dinv,
                                              const int* __restrict__ ecnt, const int* __restrict__ offsets,
                                              const int* __restrict__ csr_src,
                                              h2* __restrict__ aggh, int n) {
  int node = blockIdx.x * 4 + (threadIdx.x >> 6);
  int lane = threadIdx.x & 63;                 // half2 index 0..63 (128 ch)
  if (node >= n) return;
  float dn = dinv[node];
  h2 selfv = xh[(size_t)node * 64 + lane];     // x~[node] = x[node]*dn  (self coef dn^2 = dn * x~)
  float a0 = (float)selfv[0], a1 = (float)selfv[1];
  int start = offsets[node];
  int cnt = ecnt[node];
  int j = 0;
  for (; j + 8 <= cnt; j += 8) {
    int s0 = csr_src[start + j    ], s1 = csr_src[start + j + 1];
    int s2 = csr_src[start + j + 2], s3 = csr_src[start + j + 3];
    int s4 = csr_src[start + j + 4], s5 = csr_src[start + j + 5];
    int s6 = csr_src[start + j + 6], s7 = csr_src[start + j + 7];
    h2 v0 = xh[(size_t)s0 * 64 + lane], v1 = xh[(size_t)s1 * 64 + lane];
    h2 v2 = xh[(size_t)s2 * 64 + lane], v3 = xh[(size_t)s3 * 64 + lane];
    h2 v4 = xh[(size_t)s4 * 64 + lane], v5 = xh[(size_t)s5 * 64 + lane];
    h2 v6 = xh[(size_t)s6 * 64 + lane], v7 = xh[(size_t)s7 * 64 + lane];
    h2 p = ((v0 + v1) + (v2 + v3)) + ((v4 + v5) + (v6 + v7));   // tree of v_pk_add_f16
    a0 += (float)p[0]; a1 += (float)p[1];                       // f32 flush per chunk
  }
  h2 tail = {(_Float16)0.f, (_Float16)0.f};
  for (; j < cnt; j++) tail += xh[(size_t)csr_src[start + j] * 64 + lane];
  a0 += (float)tail[0]; a1 += (float)tail[1];
  a0 *= dn; a1 *= dn;
  h2 o; o[0] = (_Float16)a0; o[1] = (_Float16)a1;
  aggh[(size_t)node * 64 + lane] = o;
}

// ---------------- GEMM1 (MFMA): h1 = relu(agg1 @ W1 + b1). B frags lane-contiguous from swizzled W1s ----------------
__global__ __launch_bounds__(256) void k_gemm1(const _Float16* __restrict__ aggh,
                                               const _Float16* __restrict__ W1s, const float* __restrict__ b1,
                                               _Float16* __restrict__ h1h, int n) {
  int wid = threadIdx.x >> 6, lane = threadIdx.x & 63;
  int quad = lane >> 4, mrow = lane & 15;
  int mbase = blockIdx.x * 64 + wid * 16;
  int node = mbase + mrow; if (node >= n) node = n - 1;   // clamp: garbage rows never stored
  const half8* A = (const half8*)aggh;                    // [node][k] ; 16 half8 per row
  const half8* B = (const half8*)W1s;                     // swizzled: frag(nt,ks) at [(nt*4+ks)*64 + lane]
  f32x4 acc[16];
  #pragma unroll
  for (int t = 0; t < 16; t++) acc[t] = (f32x4){0.f, 0.f, 0.f, 0.f};
  #pragma unroll
  for (int ks = 0; ks < 4; ks++) {                        // K = 4 x 32
    half8 a = A[(size_t)node * 16 + ks * 4 + quad];       // A[m=lane&15][k=quad*8+j]
    #pragma unroll
    for (int nt = 0; nt < 16; nt++) {
      half8 b = B[(nt * 4 + ks) * 64 + lane];             // coalesced 1KB load, L2-resident
      acc[nt] = __builtin_amdgcn_mfma_f32_16x16x32_f16(a, b, acc[nt], 0, 0, 0);
    }
  }
  #pragma unroll
  for (int nt = 0; nt < 16; nt++) {
    int c = nt * 16 + mrow;                               // C/D: col = lane&15
    float bias = b1[c];
    #pragma unroll
    for (int r = 0; r < 4; r++) {
      int m = mbase + quad * 4 + r;                       // C/D: row = quad*4 + reg
      if (m < n) h1h[(size_t)m * H1 + c] = (_Float16)fmaxf(acc[nt][r] + bias, 0.f);
    }
  }
}

// ---------------- GEMM2 (MFMA): h2~ = (h1 @ W2) * dinv[m]. B frags from swizzled W2s ----------------
__global__ __launch_bounds__(256) void k_gemm2(const _Float16* __restrict__ h1h,
                                               const _Float16* __restrict__ W2s, const float* __restrict__ dinv,
                                               _Float16* __restrict__ h2h, int n) {
  int wid = threadIdx.x >> 6, lane = threadIdx.x & 63;
  int quad = lane >> 4, mrow = lane & 15;
  int mbase = blockIdx.x * 64 + wid * 16;
  int node = mbase + mrow; if (node >= n) node = n - 1;
  const half8* A = (const half8*)h1h;                     // [node][k] ; 32 half8 per row
  const half8* B = (const half8*)W2s;                     // swizzled: frag(nt,ks) at [(nt*8+ks)*64 + lane]
  f32x4 acc[2];
  acc[0] = (f32x4){0.f, 0.f, 0.f, 0.f};
  acc[1] = (f32x4){0.f, 0.f, 0.f, 0.f};
  #pragma unroll
  for (int ks = 0; ks < 8; ks++) {                        // K = 8 x 32
    half8 a = A[(size_t)node * 32 + ks * 4 + quad];
    #pragma unroll
    for (int nt = 0; nt < 2; nt++) {
      half8 b = B[(nt * 8 + ks) * 64 + lane];             // coalesced, 16KB table L1-resident
      acc[nt] = __builtin_amdgcn_mfma_f32_16x16x32_f16(a, b, acc[nt], 0, 0, 0);
    }
  }
  #pragma unroll
  for (int nt = 0; nt < 2; nt++) {
    int c = nt * 16 + mrow;
    #pragma unroll
    for (int r = 0; r < 4; r++) {
      int m = mbase + quad * 4 + r;
      if (m < n) h2h[(size_t)m * H2 + c] = (_Float16)(acc[nt][r] * dinv[m]);  // pre-scaled for agg2
    }
  }
}

// ---------------- layer-2 aggregation: z = dn*(sum h2~[s] + h2~[node]) + b2  (16 lanes/node) ----------------
__global__ __launch_bounds__(256) void k_agg2(const h2* __restrict__ h2h2, const float* __restrict__ dinv,
                                              const int* __restrict__ ecnt, const int* __restrict__ offsets,
                                              const int* __restrict__ csr_src,
                                              const float* __restrict__ b2, h2* __restrict__ zh2, int n) {
  int node = blockIdx.x * 16 + (threadIdx.x >> 4);
  int c2 = threadIdx.x & 15;                   // half2 index 0..15 (32 ch)
  if (node >= n) return;
  float dn = dinv[node];
  h2 selfv = h2h2[(size_t)node * 16 + c2];
  float a0 = (float)selfv[0], a1 = (float)selfv[1];
  int start = offsets[node];
  int cnt = ecnt[node];
  int j = 0;
  for (; j + 8 <= cnt; j += 8) {
    int s0 = csr_src[start + j    ], s1 = csr_src[start + j + 1];
    int s2 = csr_src[start + j + 2], s3 = csr_src[start + j + 3];
    int s4 = csr_src[start + j + 4], s5 = csr_src[start + j + 5];
    int s6 = csr_src[start + j + 6], s7 = csr_src[start + j + 7];
    h2 v0 = h2h2[(size_t)s0 * 16 + c2], v1 = h2h2[(size_t)s1 * 16 + c2];
    h2 v2 = h2h2[(size_t)s2 * 16 + c2], v3 = h2h2[(size_t)s3 * 16 + c2];
    h2 v4 = h2h2[(size_t)s4 * 16 + c2], v5 = h2h2[(size_t)s5 * 16 + c2];
    h2 v6 = h2h2[(size_t)s6 * 16 + c2], v7 = h2h2[(size_t)s7 * 16 + c2];
    h2 p = ((v0 + v1) + (v2 + v3)) + ((v4 + v5) + (v6 + v7));
    a0 += (float)p[0]; a1 += (float)p[1];
  }
  h2 tail = {(_Float16)0.f, (_Float16)0.f};
  for (; j < cnt; j++) tail += h2h2[(size_t)csr_src[start + j] * 16 + c2];
  a0 += (float)tail[0]; a1 += (float)tail[1];
  a0 = a0 * dn + b2[2 * c2];
  a1 = a1 * dn + b2[2 * c2 + 1];
  h2 o; o[0] = (_Float16)a0; o[1] = (_Float16)a1;
  zh2[(size_t)node * 16 + c2] = o;
}

// ---------------- decode: out[p] = dot(z[a], z[b])  (16 lanes/pair, fdot2) ----------------
__global__ __launch_bounds__(256) void k_decode(const h2* __restrict__ zh2, const int* __restrict__ eli,
                                                float* __restrict__ out, int L) {
  int p = blockIdx.x * 16 + (threadIdx.x >> 4);
  int c2 = threadIdx.x & 15;
  if (p >= L) return;
  int a = eli[p], b = eli[L + p];
  h2 za = zh2[(size_t)a * 16 + c2];
  h2 zb = zh2[(size_t)b * 16 + c2];
  float v = __builtin_amdgcn_fdot2(za, zb, 0.f, false);
  #pragma unroll
  for (int off = 8; off >= 1; off >>= 1) v += __shfl_xor(v, off, 64);  // stays within 16-lane group
  if (c2 == 0) out[p] = v;
}

extern "C" void kernel_launch(void* const* d_in, const int* in_sizes, int n_in,
                              void* d_out, int out_size, void* d_ws, size_t ws_size,
                              hipStream_t stream) {
  const float* x   = (const float*)d_in[0];
  const int*   ei  = (const int*)d_in[1];
  const int*   eli = (const int*)d_in[2];
  const float* W1  = (const float*)d_in[3];
  const float* b1  = (const float*)d_in[4];
  const float* W2  = (const float*)d_in[5];
  const float* b2  = (const float*)d_in[6];
  float* out = (float*)d_out;

  const int N = in_sizes[0] / IN_C;
  const int E = in_sizes[1] / 2;
  const int L = in_sizes[2] / 2;
  const int* e_src = ei;
  const int* e_dst = ei + E;
  const int NB = (N + 255) >> BWL;

  char* p = (char*)d_ws;
  auto carve = [&](size_t bytes) -> void* {
    void* r = (void*)p;
    p += (bytes + 255) & ~(size_t)255;
    return r;
  };
  int*   ecnt      = (int*)  carve((size_t)N * 4);
  float* dinv      = (float*)carve((size_t)N * 4);
  int*   offsets   = (int*)  carve((size_t)N * 4);
  int*   bcnt      = (int*)  carve(NBMAX * 4);
  int*   bbase     = (int*)  carve((NBMAX + 1) * 4);
  int*   bcursor   = (int*)  carve(NBMAX * 4);
  _Float16* W1s    = (_Float16*)carve(256 * 128 * 2);         // 64 KB, fragment-swizzled
  _Float16* W2s    = (_Float16*)carve(32 * 256 * 2);          // 16 KB, fragment-swizzled
  int*   csr_src   = (int*)  carve((size_t)E * 4);            // 6.4 MB
  h2*    xh        = (h2*)   carve((size_t)N * IN_C * 2);     // 12.8 MB
  h2*    aggh      = (h2*)   carve(((size_t)N + 64) * IN_C * 2); // 12.8 MB (+pad rows for clamped loads)
  __half* h1h      = (__half*)carve(((size_t)N + 64) * H1 * 2);  // 25.6 MB
  unsigned long long* binned = (unsigned long long*)h1h;      // alias: dead before gemm1 writes h1h
  _Float16* h2h = (_Float16*)aggh;                            // alias: aggh dead after gemm1 reads it
  h2*    h2h2 = (h2*)aggh;
  h2*    zh2 = (h2*)((char*)aggh + (size_t)N * H2 * 2);

  const int B = 256;
  k_init<<<1, B, 0, stream>>>(bcnt, bcursor, NB);
  k_castw<<<128, B, 0, stream>>>(W1, W2, W1s, W2s);
  k_bin<<<(E + 2047) / 2048, B, 0, stream>>>(e_dst, bcnt, E, NB);
  k_scan_bkt<<<1, B, 0, stream>>>(bcnt, bbase, NB);
  k_scatter<<<(E + 4095) / 4096, B, 0, stream>>>(e_src, e_dst, bbase, bcursor, binned, E, NB);
  k_fill2<<<NB, B, 0, stream>>>(binned, bbase, csr_src, offsets, ecnt, dinv, N, NB);
  k_cast<<<(N * IN_C / 4 + B - 1) / B, B, 0, stream>>>((const float4*)x, dinv, xh, N * IN_C / 4);
  k_agg1<<<(N + 3) / 4, B, 0, stream>>>(xh, dinv, ecnt, offsets, csr_src, aggh, N);
  k_gemm1<<<(N + 63) / 64, B, 0, stream>>>((const _Float16*)aggh, W1s, b1, (_Float16*)h1h, N);
  k_gemm2<<<(N + 63) / 64, B, 0, stream>>>((const _Float16*)h1h, W2s, dinv, h2h, N);
  k_agg2<<<(N + 15) / 16, B, 0, stream>>>(h2h2, dinv, ecnt, offsets, csr_src, b2, zh2, N);
  k_decode<<<(L + 15) / 16, B, 0, stream>>>(zh2, eli, out, L);
}